// Round 14
// baseline (341.000 us; speedup 1.0000x reference)
//
#include <hip/hip_runtime.h>
#include <math.h>

// ---------------- problem constants ----------------
static constexpr int NB = 2;
static constexpr int NC = 64;
static constexpr int NHp = 128, NWp = 128;
static constexpr int NL = NHp * NWp;     // 16384
static constexpr int NCR = 16;
static constexpr int NL2 = 64 * 64;      // 4096
static constexpr int NHASH = 4;
static constexpr int CHUNKSZ = 512;
static constexpr int NCHUNKS = 32;
static constexpr int TOT = NHASH * NL;   // 65536
static constexpr int NKEY = 128;
static constexpr int NTILE = 256;
static constexpr int TILESZ = TOT / NTILE; // 256

typedef _Float16 half4 __attribute__((ext_vector_type(4)));
typedef _Float16 half8 __attribute__((ext_vector_type(8)));
typedef float f32x4 __attribute__((ext_vector_type(4)));

#if __has_builtin(__builtin_amdgcn_exp2f)
  #define EXP2F(x) __builtin_amdgcn_exp2f(x)
#else
  #define EXP2F(x) __expf(0.69314718f*(x))
#endif

// ---------------- workspace layout (float units) ----------------
static constexpr size_t OFF_MASK = 0;
static constexpr size_t OFF_FEA  = OFF_MASK + (size_t)NB*NC*NL;
static constexpr size_t OFF_XE   = OFF_FEA  + (size_t)NB*NC*NL;
static constexpr size_t OFF_XEH  = OFF_XE   + (size_t)NB*NL*NCR;
static constexpr size_t OFF_XENH = OFF_XEH  + (size_t)NB*NL*NCR/2;
static constexpr size_t OFF_VS   = OFF_XENH + (size_t)NB*NL*NCR/2;
static constexpr size_t OFF_RET  = OFF_VS   + (size_t)NB*TOT*NC/2;
static constexpr size_t OFF_BSC  = OFF_RET  + (size_t)NB*TOT*NC/2;
static constexpr size_t OFF_INT  = OFF_BSC  + (size_t)NB*TOT;
static constexpr size_t IOFF_CODES = 0;
static constexpr size_t IOFF_IDX   = IOFF_CODES + (size_t)NB*TOT;
static constexpr size_t IOFF_UNDO  = IOFF_IDX   + (size_t)NB*TOT;
static constexpr size_t IOFF_HIST  = IOFF_UNDO  + (size_t)NB*TOT;
static constexpr size_t IOFF_OFFS  = IOFF_HIST  + (size_t)NB*NKEY*NTILE/2;
static constexpr size_t IOFF_END   = IOFF_OFFS  + (size_t)NB*NKEY*NTILE/2;
static constexpr size_t OFF_CAY = OFF_INT + IOFF_END;
static constexpr size_t OFF_CAS = OFF_CAY + 128;
static constexpr size_t OFF_CRW = OFF_CAS + 128;
static constexpr size_t OFF_CRB = OFF_CRW + 4096;
static constexpr size_t OFF_QS = OFF_FEA;
static constexpr size_t OFF_KS = OFF_QS + (size_t)NB*TOT*NCR/2;
static_assert(OFF_KS + (size_t)NB*TOT*NCR/2 <= OFF_XE, "qs/ks fit in fea region");
static constexpr size_t OFF_PTMP  = OFF_FEA;
static constexpr size_t OFF_DWT   = OFF_PTMP + (size_t)6*NB*NCR*NL2;
static_assert(OFF_DWT + (size_t)6*NB*NCR*NL2 <= OFF_XE, "halfres overlay fits");
static constexpr size_t OFF_XR    = OFF_XE;
static constexpr size_t OFF_FEATS = OFF_XR + (size_t)NB*NCR*NL;
static_assert(OFF_FEATS + (size_t)NB*128*NL <= OFF_RET, "feats overlay fits");
static constexpr size_t OFF_PRE1  = OFF_FEA;

__device__ __forceinline__ float sigmoidf_(float v){ return 1.0f/(1.0f + expf(-v)); }

// ---------------- phase 1 ----------------

__global__ __launch_bounds__(256,4) void k_xr(const float* __restrict__ x,
                     const float* __restrict__ w,
                     const float* __restrict__ b, float* __restrict__ xr){
  int gid = blockIdx.x*256 + threadIdx.x;
  int pix = gid >> 1, hf = gid & 1;
  int bb = pix >> 14, p = pix & (NL-1);
  const float* xi = x + (size_t)bb*NC*NL + (size_t)hf*32*NL + p;
  float acc[16];
  #pragma unroll
  for (int oc=0; oc<16; ++oc) acc[oc] = hf ? 0.f : b[oc];
  for (int ic0=0; ic0<32; ic0+=16){
    float r[16];
    #pragma unroll
    for (int j=0; j<16; ++j) r[j] = xi[(size_t)(ic0+j)*NL];
    #pragma unroll
    for (int oc=0; oc<16; ++oc){
      #pragma unroll
      for (int j=0; j<16; ++j) acc[oc] += r[j]*w[oc*64 + hf*32 + ic0 + j];
    }
  }
  #pragma unroll
  for (int oc=0; oc<16; ++oc) acc[oc] += __shfl_xor(acc[oc], 1, 64);
  if (!hf){
    float* xo = xr + (size_t)bb*NCR*NL + p;
    #pragma unroll
    for (int oc=0; oc<16; ++oc) xo[(size_t)oc*NL] = acc[oc];
  }
}

__global__ __launch_bounds__(256,4) void k_s0(const float* __restrict__ xr,
                     const float* __restrict__ pw,
                     const float* __restrict__ dww, const float* __restrict__ dwb,
                     float* __restrict__ feats){
  int gid = blockIdx.x*256 + threadIdx.x;
  int oc0 = blockIdx.y*16;
  int bb = gid >> 14, p = gid & (NL-1);
  const float* xi = xr + (size_t)bb*NCR*NL + p;
  float r[16];
  #pragma unroll
  for (int ic=0; ic<16; ++ic) r[ic] = xi[(size_t)ic*NL];
  float* fo = feats + (size_t)bb*128*NL + p;
  #pragma unroll
  for (int j=0; j<16; ++j){
    int oc = oc0 + j;
    float s = 0.f;
    #pragma unroll
    for (int ic=0; ic<16; ++ic) s += r[ic]*pw[oc*16+ic];
    fo[(size_t)oc*NL] = s*dww[oc] + dwb[oc];
  }
}

__global__ void k_pw16_all(const float* __restrict__ xr,
                           const float* __restrict__ w0, const float* __restrict__ w1,
                           const float* __restrict__ w2, float* __restrict__ out){
  int gid = blockIdx.x*256 + threadIdx.x;
  if (gid >= 6*NB*NL2) return;
  int p = gid & (NL2-1); int t = gid >> 12; int bb = t & 1; int combo = t >> 1;
  int br = combo >> 1, mode = combo & 1;
  const float* w = (br==0) ? w0 : (br==1) ? w1 : w2;
  int y = p >> 6, x2 = p & 63;
  float r[16];
  #pragma unroll
  for (int ic=0; ic<16; ++ic){
    const float* base = xr + (size_t)(bb*NCR + ic)*NL + (size_t)(2*y)*NWp + 2*x2;
    float a = base[0], b_ = base[1], c_ = base[NWp], d = base[NWp+1];
    r[ic] = mode ? 0.25f*(a+b_+c_+d) : fmaxf(fmaxf(a,b_), fmaxf(c_,d));
  }
  float* oo = out + ((size_t)(combo*NB + bb)*NCR)*NL2 + p;
  #pragma unroll
  for (int oc=0; oc<16; ++oc){
    float s = 0.f;
    #pragma unroll
    for (int ic=0; ic<16; ++ic) s += r[ic]*w[oc*16+ic];
    oo[(size_t)oc*NL2] = s;
  }
}

__global__ void k_dw_all(const float* __restrict__ in,
                         const float* __restrict__ w3, const float* __restrict__ b3,
                         const float* __restrict__ w5, const float* __restrict__ b5,
                         const float* __restrict__ w7, const float* __restrict__ b7,
                         float* __restrict__ out){
  int gid = blockIdx.x*256 + threadIdx.x;
  if (gid >= 6*NB*NCR*NL2) return;
  int p = gid & (NL2-1); int t = gid >> 12; int c = t & 15; int r2 = t >> 4;
  int bb = r2 & 1; int combo = r2 >> 1;
  int br = combo >> 1;
  int K = (br==0) ? 3 : (br==1) ? 5 : 7; int P = K >> 1;
  const float* w = (br==0) ? w3 : (br==1) ? w5 : w7;
  const float* bias = (br==0) ? b3 : (br==1) ? b5 : b7;
  int y = p >> 6, x = p & 63;
  const float* xi = in + ((size_t)(combo*NB + bb)*NCR + c)*NL2;
  float s = bias[c];
  for (int dy=0; dy<K; ++dy){
    int iy = y + dy - P;
    if ((unsigned)iy < 64u){
      for (int dx=0; dx<K; ++dx){
        int ix = x + dx - P;
        if ((unsigned)ix < 64u) s += xi[iy*64 + ix] * w[(c*K + dy)*K + dx];
      }
    }
  }
  out[gid] = s;
}

__global__ void k_up_all(const float* __restrict__ in, float* __restrict__ feats){
  int gid = blockIdx.x*256 + threadIdx.x;
  if (gid >= 6*NB*NCR*NL) return;
  int p = gid & (NL-1); int t = gid >> 14; int c = t & 15; int r2 = t >> 4;
  int bb = r2 & 1; int combo = r2 >> 1;
  int y = p >> 7, x = p & 127;
  const float sc = 63.0f/127.0f;
  float fy = y*sc; int ly = (int)floorf(fy); int hy = min(ly+1, 63); fy -= (float)ly;
  float fx = x*sc; int lx = (int)floorf(fx); int hx = min(lx+1, 63); float gx = fx - (float)lx;
  const float* xi = in + ((size_t)(combo*NB + bb)*NCR + c)*NL2;
  float v0 = xi[ly*64+lx]*(1.f-fy) + xi[hy*64+lx]*fy;
  float v1 = xi[ly*64+hx]*(1.f-fy) + xi[hy*64+hx]*fy;
  int coff = 32 + combo*16 + c;
  feats[(size_t)bb*128*NL + (size_t)coff*NL + p] = v0*(1.f-gx) + v1*gx;
}

__global__ void k_camean(const float* __restrict__ x, float* __restrict__ cay){
  __shared__ float red[256];
  int bc = blockIdx.x; int tid = threadIdx.x;
  float s = 0.f;
  for (int i = tid; i < NL; i += 256) s += x[(size_t)bc*NL + i];
  red[tid] = s; __syncthreads();
  for (int st=128; st>0; st>>=1){ if (tid<st) red[tid]+=red[tid+st]; __syncthreads(); }
  if (tid==0) cay[bc] = red[0] / (float)NL;
}

__global__ void k_camlp(const float* __restrict__ cay,
                        const float* __restrict__ w1, const float* __restrict__ b1,
                        const float* __restrict__ w2, const float* __restrict__ b2,
                        float* __restrict__ cas){
  __shared__ float z[NB*4];
  int tid = threadIdx.x;
  if (tid < NB*4){
    int bb = tid >> 2, j = tid & 3;
    float s = b1[j];
    for (int ic=0; ic<NC; ++ic) s += cay[bb*NC+ic]*w1[j*NC+ic];
    z[tid] = fmaxf(s, 0.f);
  }
  __syncthreads();
  if (tid < NB*NC){
    int bb = tid >> 6, oc = tid & 63;
    float s = b2[oc];
    #pragma unroll
    for (int j=0; j<4; ++j) s += z[bb*4+j]*w2[oc*4+j];
    cas[tid] = sigmoidf_(s);
  }
}

__global__ void k_wprod(const float* __restrict__ c11w, const float* __restrict__ c11b,
                        const float* __restrict__ rw, const float* __restrict__ rb,
                        float* __restrict__ crw, float* __restrict__ crb){
  int gid = blockIdx.x*256 + threadIdx.x;
  if (gid >= 4096) return;
  int o = gid >> 6, i = gid & 63;
  float s = 0.f;
  for (int k=0; k<64; ++k) s += c11w[o*64+k]*rw[k*64+i];
  crw[gid] = s;
  if (i == 0){
    float t = c11b[o];
    for (int k=0; k<64; ++k) t += c11w[o*64+k]*rb[k];
    crb[o] = t;
  }
}

// LDS-tiled attnmul: 512 thr, 64-px tile, feats staged once (32 KB)
__global__ __launch_bounds__(512) void k_attnmul(const float* __restrict__ x,
                          const float* __restrict__ feats,
                          const float* __restrict__ fw, const float* __restrict__ fb,
                          const float* __restrict__ cas, float* __restrict__ pre1){
  __shared__ float fs[128][64];
  int blk = blockIdx.x;                 // NB*NL/64 = 512
  int bb = blk >> 8; int px0 = (blk & 255)*64;
  int tid = threadIdx.x;
  const float* fbase = feats + (size_t)bb*128*NL + px0;
  for (int i = tid; i < 128*64; i += 512){
    int k = i >> 6, p = i & 63;
    fs[k][p] = fbase[(size_t)k*NL + p];
  }
  __syncthreads();
  int px = tid & 63, oc0 = (tid >> 6)*8;
  float acc[8];
  #pragma unroll
  for (int j=0; j<8; ++j) acc[j] = fb[oc0+j];
  for (int k0=0; k0<128; k0+=8){
    float fr[8];
    #pragma unroll
    for (int t=0; t<8; ++t) fr[t] = fs[k0+t][px];
    #pragma unroll
    for (int j=0; j<8; ++j){
      #pragma unroll
      for (int t=0; t<8; ++t) acc[j] += fr[t]*fw[(oc0+j)*128+k0+t];
    }
  }
  const float* xb = x + (size_t)bb*NC*NL + px0 + px;
  float* po = pre1 + (size_t)bb*NC*NL + px0 + px;
  #pragma unroll
  for (int j=0; j<8; ++j){
    int oc = oc0 + j;
    float xv = xb[(size_t)oc*NL];
    po[(size_t)oc*NL] = xv*(sigmoidf_(acc[j]) + cas[bb*64+oc]);
  }
}

// LDS-tiled mask: pre1 + x tiles staged once (32 KB)
__global__ __launch_bounds__(512) void k_mask(const float* __restrict__ pre1,
                       const float* __restrict__ c11w,
                       const float* __restrict__ crw, const float* __restrict__ crb,
                       const float* __restrict__ x, float* __restrict__ mask){
  __shared__ float ps[64][64];
  __shared__ float xs[64][64];
  int blk = blockIdx.x;
  int bb = blk >> 8; int px0 = (blk & 255)*64;
  int tid = threadIdx.x;
  const float* pbase = pre1 + (size_t)bb*NC*NL + px0;
  const float* xbase = x + (size_t)bb*NC*NL + px0;
  for (int i = tid; i < 64*64; i += 512){
    int c = i >> 6, p = i & 63;
    ps[c][p] = pbase[(size_t)c*NL + p];
    xs[c][p] = xbase[(size_t)c*NL + p];
  }
  __syncthreads();
  int px = tid & 63, oc0 = (tid >> 6)*8;
  float acc[8];
  #pragma unroll
  for (int j=0; j<8; ++j) acc[j] = crb[oc0+j];
  for (int ic0=0; ic0<64; ic0+=8){
    float pr[8], xr8[8];
    #pragma unroll
    for (int t=0; t<8; ++t){ pr[t] = ps[ic0+t][px]; xr8[t] = xs[ic0+t][px]; }
    #pragma unroll
    for (int j=0; j<8; ++j){
      #pragma unroll
      for (int t=0; t<8; ++t)
        acc[j] += pr[t]*c11w[(oc0+j)*64+ic0+t] + xr8[t]*crw[(oc0+j)*64+ic0+t];
    }
  }
  float* mo = mask + (size_t)bb*NC*NL + px0 + px;
  #pragma unroll
  for (int j=0; j<8; ++j){
    int oc = oc0 + j;
    mo[(size_t)oc*NL] = acc[j] + xs[oc][px];
  }
}

// ---------------- phase 2 ----------------

__global__ __launch_bounds__(256,4) void k_xe(const float* __restrict__ mask,
                     const float* __restrict__ w, const float* __restrict__ b,
                     const float* __restrict__ rot,
                     _Float16* __restrict__ xeh, _Float16* __restrict__ xenh,
                     int* __restrict__ codes, int* __restrict__ hist){
  int gid = blockIdx.x*256 + threadIdx.x;
  int pix = gid >> 1, hf = gid & 1;
  int bb = pix >> 14, l = pix & (NL-1);
  const float* mi = mask + (size_t)bb*NC*NL + (size_t)hf*32*NL + l;
  float acc[16];
  #pragma unroll
  for (int oc=0; oc<16; ++oc) acc[oc] = hf ? 0.f : b[oc];
  for (int ic0=0; ic0<32; ic0+=16){
    float r[16];
    #pragma unroll
    for (int j=0; j<16; ++j) r[j] = mi[(size_t)(ic0+j)*NL];
    #pragma unroll
    for (int oc=0; oc<16; ++oc){
      #pragma unroll
      for (int j=0; j<16; ++j) acc[oc] += r[j]*w[oc*64 + hf*32 + ic0 + j];
    }
  }
  #pragma unroll
  for (int oc=0; oc<16; ++oc) acc[oc] += __shfl_xor(acc[oc], 1, 64);
  if (!hf){
    float n2 = 0.f;
    #pragma unroll
    for (int oc=0; oc<16; ++oc) n2 += acc[oc]*acc[oc];
    float inv = 1.0f / fmaxf(sqrtf(n2), 5e-5f);
    _Float16* ho = xeh + (size_t)pix*NCR;
    _Float16* no = xenh + (size_t)pix*NCR;
    #pragma unroll
    for (int g=0; g<4; ++g){
      half4 hv, nv;
      #pragma unroll
      for (int j=0; j<4; ++j){ hv[j] = (_Float16)acc[g*4+j]; nv[j] = (_Float16)(acc[g*4+j]*inv); }
      *(half4*)(ho + g*4) = hv;
      *(half4*)(no + g*4) = nv;
    }
  }
  #pragma unroll
  for (int hh=0; hh<2; ++hh){
    int h = hf*2 + hh;
    float rv[16];
    #pragma unroll
    for (int i=0; i<16; ++i){
      float s = 0.f;
      #pragma unroll
      for (int f=0; f<16; ++f) s += acc[f]*rot[(f*NHASH + h)*16 + i];
      rv[i] = s;
    }
    float best = -1e30f; int bi = 0;
    #pragma unroll
    for (int i=0; i<16; ++i){ if (rv[i] > best){ best = rv[i]; bi = i; } }
    #pragma unroll
    for (int i=0; i<16; ++i){ float val = -rv[i]; if (val > best){ best = val; bi = 16+i; } }
    int code = bi + h*32;
    codes[((bb*NHASH + h) << 14) + l] = code;
    int tile = h*64 + (l >> 8);
    atomicAdd(&hist[bb*NKEY*NTILE + code*NTILE + tile], 1);
  }
}

// LDS-tiled yeh: mask tile staged once (16 KB); scatter to sorted V
__global__ __launch_bounds__(512) void k_yeh(const float* __restrict__ mask,
                      const float* __restrict__ w, const float* __restrict__ b,
                      const int* __restrict__ undo, _Float16* __restrict__ vs){
  __shared__ float ms[64][64];
  int blk = blockIdx.x;
  int bb = blk >> 8; int px0 = (blk & 255)*64;
  int tid = threadIdx.x;
  const float* mbase = mask + (size_t)bb*NC*NL + px0;
  for (int i = tid; i < 64*64; i += 512){
    int c = i >> 6, p = i & 63;
    ms[c][p] = mbase[(size_t)c*NL + p];
  }
  __syncthreads();
  int px = tid & 63, oc0 = (tid >> 6)*8;
  float acc[8];
  #pragma unroll
  for (int j=0; j<8; ++j) acc[j] = b[oc0+j];
  for (int ic0=0; ic0<64; ic0+=8){
    float r[8];
    #pragma unroll
    for (int t=0; t<8; ++t) r[t] = ms[ic0+t][px];
    #pragma unroll
    for (int j=0; j<8; ++j){
      #pragma unroll
      for (int t=0; t<8; ++t) acc[j] += r[t]*w[(oc0+j)*64+ic0+t];
    }
  }
  half8 hv;
  #pragma unroll
  for (int j=0; j<8; ++j) hv[j] = (_Float16)acc[j];
  int l = px0 + px;
  const int* ub = undo + bb*TOT;
  #pragma unroll
  for (int h=0; h<4; ++h){
    int pos = ub[h*NL + l];
    *(half8*)(vs + ((size_t)bb*TOT + pos)*64 + oc0) = hv;
  }
}

__global__ void k_scan(const int* __restrict__ hist, int* __restrict__ offs){
  __shared__ int part[256];
  int bb = blockIdx.x; int t = threadIdx.x;
  const int* hi = hist + (size_t)bb*NKEY*NTILE;
  int* oo = offs + (size_t)bb*NKEY*NTILE;
  int s = 0;
  for (int i=0; i<128; ++i) s += hi[t*128 + i];
  part[t] = s; __syncthreads();
  int v = s;
  for (int off=1; off<256; off<<=1){
    int u = (t >= off) ? part[t-off] : 0;
    __syncthreads();
    v += u; part[t] = v;
    __syncthreads();
  }
  int run = v - s;
  for (int i=0; i<128; ++i){ int q = hi[t*128+i]; oo[t*128+i] = run; run += q; }
}

__global__ __launch_bounds__(256) void k_scatter(const int* __restrict__ codes,
                          const int* __restrict__ offs,
                          const _Float16* __restrict__ xeh, const _Float16* __restrict__ xenh,
                          int* __restrict__ idx, int* __restrict__ undo,
                          _Float16* __restrict__ qs, _Float16* __restrict__ ks){
  __shared__ int cnt[4][NKEY];
  int wid = threadIdx.x >> 6, lane = threadIdx.x & 63;
  int t4 = blockIdx.x;
  int bb = t4 >> 6;
  int tile = (t4 & 63)*4 + wid;
  cnt[wid][lane] = 0; cnt[wid][64+lane] = 0;
  const int* cb = codes + bb*TOT;
  const int* ob = offs + (size_t)bb*NKEY*NTILE;
  int* ib = idx + bb*TOT;
  int* ub = undo + bb*TOT;
  for (int g=0; g<4; ++g){
    int j = tile*TILESZ + g*64 + lane;
    int k = cb[j];
    unsigned long long m = ~0ull;
    #pragma unroll
    for (int bit=0; bit<7; ++bit){
      unsigned long long bmask = __ballot((k >> bit) & 1);
      m &= ((k >> bit) & 1) ? bmask : ~bmask;
    }
    int rank = __popcll(m & ((1ull << lane) - 1ull));
    int leader = __ffsll((unsigned long long)m) - 1;
    int base = 0;
    if (lane == leader){
      base = cnt[wid][k];
      cnt[wid][k] = base + __popcll(m);
    }
    base = __shfl(base, leader, 64);
    int pos = ob[k*NTILE + tile] + base + rank;
    ib[pos] = j;
    ub[j] = pos;
    int l = j & (NL-1);
    const _Float16* qp = xeh + ((size_t)bb*NL + l)*16;
    const _Float16* kp = xenh + ((size_t)bb*NL + l)*16;
    _Float16* qo = qs + ((size_t)bb*TOT + pos)*16;
    _Float16* ko = ks + ((size_t)bb*TOT + pos)*16;
    *(half8*)(qo)     = *(const half8*)(qp);
    *(half8*)(qo + 8) = *(const half8*)(qp + 8);
    *(half8*)(ko)     = *(const half8*)(kp);
    *(half8*)(ko + 8) = *(const half8*)(kp + 8);
    __threadfence_block();
  }
}

// MFMA flash attention (unchanged from round 13)
__global__ __launch_bounds__(512) void k_attn(
    const _Float16* __restrict__ qs, const _Float16* __restrict__ ks,
    const _Float16* __restrict__ vs,
    _Float16* __restrict__ retb, float* __restrict__ bsc){
  __shared__ _Float16 kt[64*20];
  __shared__ _Float16 vt[64*70];
  int blk = blockIdx.x;
  int qh = blk & 1; int kk = (blk >> 1) & 31; int h = (blk >> 6) & 3; int bb = blk >> 8;
  int tid = threadIdx.x;
  int w = tid >> 6, lane = tid & 63, col = lane & 15, grp = lane >> 4;
  int qbase = h*NL + kk*CHUNKSZ + qh*256 + w*32;

  half4 qfr[2]; int posq[2];
  #pragma unroll
  for (int qf=0; qf<2; ++qf){
    posq[qf] = qbase + qf*16 + col;
    qfr[qf] = *(const half4*)(qs + ((size_t)bb*TOT + posq[qf])*16 + grp*4);
    #pragma unroll
    for (int i=0; i<4; ++i) qfr[qf][i] = (_Float16)((float)qfr[qf][i] * 1.44269504f);
  }

  f32x4 O[4][2];
  #pragma unroll
  for (int a=0; a<4; ++a)
    #pragma unroll
    for (int b=0; b<2; ++b) O[a][b] = (f32x4){0.f,0.f,0.f,0.f};
  float m_[2] = {-1e30f,-1e30f};
  float ssum[2] = {0.f,0.f};

  int kx = tid & 63, c0 = (tid >> 6) * 8;
  int kr = tid >> 1, khf = tid & 1;

  #define SPOS(jj) ({ int sec_ = (jj) >> 9; int j0_ = (jj) & 511; \
      int cc_ = kk + ((sec_==1) ? -1 : (sec_==2) ? 1 : 0); \
      cc_ = (cc_ + NCHUNKS) & (NCHUNKS-1); h*NL + cc_*CHUNKSZ + j0_; })

  half8 vv = *(const half8*)(vs + ((size_t)bb*TOT + SPOS(kx))*64 + c0);
  half8 kv;
  if (tid < 128) kv = *(const half8*)(ks + ((size_t)bb*TOT + SPOS(kr))*16 + khf*8);

  for (int t=0; t<24; ++t){
    __syncthreads();
    #pragma unroll
    for (int j=0; j<8; ++j) vt[(c0+j)*70 + kx] = vv[j];
    if (tid < 128) *(half8*)(kt + kr*20 + khf*8) = kv;
    __syncthreads();
    if (t+1 < 24){
      int jj = (t+1)*64;
      vv = *(const half8*)(vs + ((size_t)bb*TOT + SPOS(jj + kx))*64 + c0);
      if (tid < 128) kv = *(const half8*)(ks + ((size_t)bb*TOT + SPOS(jj + kr))*16 + khf*8);
    }

    f32x4 S[4][2];
    #pragma unroll
    for (int kb=0; kb<4; ++kb){
      half4 ka = *(const half4*)(kt + (kb*16 + col)*20 + grp*4);
      #pragma unroll
      for (int qf=0; qf<2; ++qf)
        S[kb][qf] = __builtin_amdgcn_mfma_f32_16x16x16f16(
            ka, qfr[qf], (f32x4){0.f,0.f,0.f,0.f}, 0, 0, 0);
    }

    half8 pb[2][2];
    #pragma unroll
    for (int qf=0; qf<2; ++qf){
      float mtl = -1e30f;
      #pragma unroll
      for (int kb=0; kb<4; ++kb)
        #pragma unroll
        for (int i=0; i<4; ++i) mtl = fmaxf(mtl, S[kb][qf][i]);
      if (__any(mtl > m_[qf] + 11.5f)){
        float mt = fmaxf(mtl, __shfl_xor(mtl, 16, 64));
        mt = fmaxf(mt, __shfl_xor(mt, 32, 64));
        float mn = fmaxf(m_[qf], mt);
        float sc = EXP2F(m_[qf] - mn);
        ssum[qf] *= sc;
        m_[qf] = mn;
        #pragma unroll
        for (int cf=0; cf<4; ++cf)
          #pragma unroll
          for (int i=0; i<4; ++i) O[cf][qf][i] *= sc;
      }
      float ps = 0.f;
      #pragma unroll
      for (int k2=0; k2<2; ++k2){
        half8 hb;
        #pragma unroll
        for (int i=0; i<4; ++i){
          float p0 = EXP2F(S[2*k2][qf][i]   - m_[qf]);
          float p1 = EXP2F(S[2*k2+1][qf][i] - m_[qf]);
          ps += p0 + p1;
          hb[i]   = (_Float16)p0;
          hb[4+i] = (_Float16)p1;
        }
        pb[qf][k2] = hb;
      }
      ssum[qf] += ps;
    }

    #pragma unroll
    for (int cf=0; cf<4; ++cf){
      #pragma unroll
      for (int k2=0; k2<2; ++k2){
        half4 a0 = *(const half4*)(vt + (cf*16 + col)*70 + k2*32 + grp*4);
        half4 a1 = *(const half4*)(vt + (cf*16 + col)*70 + k2*32 + 16 + grp*4);
        half8 va;
        #pragma unroll
        for (int i=0; i<4; ++i){ va[i] = a0[i]; va[4+i] = a1[i]; }
        #pragma unroll
        for (int qf=0; qf<2; ++qf)
          O[cf][qf] = __builtin_amdgcn_mfma_f32_16x16x32_f16(
              va, pb[qf][k2], O[cf][qf], 0, 0, 0);
      }
    }
  }
  #undef SPOS

  #pragma unroll
  for (int qf=0; qf<2; ++qf){
    float st = ssum[qf];
    st += __shfl_xor(st, 16, 64);
    st += __shfl_xor(st, 32, 64);
    float inv = 1.0f/st;
    size_t rb = ((size_t)bb*TOT + posq[qf])*64;
    #pragma unroll
    for (int cf=0; cf<4; ++cf){
      half4 o;
      #pragma unroll
      for (int i=0; i<4; ++i) o[i] = (_Float16)(O[cf][qf][i]*inv);
      *(half4*)(retb + rb + cf*16 + grp*4) = o;
    }
    if (grp == 0) bsc[(size_t)bb*TOT + posq[qf]] = m_[qf]*0.69314718f + logf(st);
  }
}

// combine: single pass, full 64 channels per thread (halves ret reads)
__global__ __launch_bounds__(256,4) void k_combine(const _Float16* __restrict__ retb,
                          const float* __restrict__ bsc,
                          const int* __restrict__ undo, const float* __restrict__ mask,
                          float* __restrict__ fea){
  int gid = blockIdx.x*256 + threadIdx.x;
  int bb = gid >> 14; int l = gid & (NL-1);
  const int* ub = undo + bb*TOT;
  int pos[4]; float sc[4];
  #pragma unroll
  for (int h=0; h<4; ++h){ pos[h] = ub[h*NL + l]; sc[h] = bsc[bb*TOT + pos[h]]; }
  float mx = fmaxf(fmaxf(sc[0],sc[1]), fmaxf(sc[2],sc[3]));
  float e[4]; float tot = 0.f;
  #pragma unroll
  for (int h=0; h<4; ++h){ e[h] = __expf(sc[h]-mx); tot += e[h]; }
  float inv = 0.1f/tot;
  const float* mb_ = mask + (size_t)bb*NC*NL + l;
  float* fo = fea + (size_t)bb*NC*NL + l;
  const _Float16* r0 = retb + ((size_t)bb*TOT + pos[0])*NC;
  const _Float16* r1 = retb + ((size_t)bb*TOT + pos[1])*NC;
  const _Float16* r2 = retb + ((size_t)bb*TOT + pos[2])*NC;
  const _Float16* r3 = retb + ((size_t)bb*TOT + pos[3])*NC;
  for (int g=0; g<8; ++g){
    half8 v0 = *(const half8*)(r0 + g*8);
    half8 v1 = *(const half8*)(r1 + g*8);
    half8 v2 = *(const half8*)(r2 + g*8);
    half8 v3 = *(const half8*)(r3 + g*8);
    #pragma unroll
    for (int j=0; j<8; ++j){
      int c = g*8 + j;
      float v = (float)v0[j]*e[0] + (float)v1[j]*e[1] + (float)v2[j]*e[2] + (float)v3[j]*e[3];
      fo[(size_t)c*NL] = v*inv + mb_[(size_t)c*NL];
    }
  }
}

// LDS-tiled collect: fea tile staged once (16 KB)
__global__ __launch_bounds__(512) void k_collect(const float* __restrict__ fea,
                          const float* __restrict__ w,
                          const float* __restrict__ b, const float* __restrict__ x,
                          float* __restrict__ out){
  __shared__ float fs[64][64];
  int blk = blockIdx.x;
  int bb = blk >> 8; int px0 = (blk & 255)*64;
  int tid = threadIdx.x;
  const float* fbase = fea + (size_t)bb*NC*NL + px0;
  for (int i = tid; i < 64*64; i += 512){
    int c = i >> 6, p = i & 63;
    fs[c][p] = fbase[(size_t)c*NL + p];
  }
  __syncthreads();
  int px = tid & 63, oc0 = (tid >> 6)*8;
  float acc[8];
  #pragma unroll
  for (int j=0; j<8; ++j) acc[j] = b[oc0+j];
  for (int ic0=0; ic0<64; ic0+=8){
    float r[8];
    #pragma unroll
    for (int t=0; t<8; ++t) r[t] = fs[ic0+t][px];
    #pragma unroll
    for (int j=0; j<8; ++j){
      #pragma unroll
      for (int t=0; t<8; ++t) acc[j] += r[t]*w[(oc0+j)*64+ic0+t];
    }
  }
  const float* xi = x + (size_t)bb*NC*NL + px0 + px;
  float* oo = out + (size_t)bb*NC*NL + px0 + px;
  #pragma unroll
  for (int j=0; j<8; ++j){
    int oc = oc0 + j;
    oo[(size_t)oc*NL] = acc[j] + xi[(size_t)oc*NL];
  }
}

// ---------------- launcher ----------------
extern "C" void kernel_launch(void* const* d_in, const int* in_sizes, int n_in,
                              void* d_out, int out_size, void* d_ws, size_t ws_size,
                              hipStream_t stream) {
  const float* x        = (const float*)d_in[0];
  const float* spa_dw   = (const float*)d_in[1];
  const float* spa_db   = (const float*)d_in[2];
  const float* s0_pw    = (const float*)d_in[3];
  const float* s0_dww   = (const float*)d_in[4];
  const float* s0_dwb   = (const float*)d_in[5];
  const float* fus_w    = (const float*)d_in[15];
  const float* fus_b    = (const float*)d_in[16];
  const float* res_w    = (const float*)d_in[17];
  const float* res_b    = (const float*)d_in[18];
  const float* ca_w1    = (const float*)d_in[19];
  const float* ca_b1    = (const float*)d_in[20];
  const float* ca_w2    = (const float*)d_in[21];
  const float* ca_b2    = (const float*)d_in[22];
  const float* c11_w    = (const float*)d_in[23];
  const float* c11_b    = (const float*)d_in[24];
  const float* match_w  = (const float*)d_in[25];
  const float* match_b  = (const float*)d_in[26];
  const float* asm_w    = (const float*)d_in[27];
  const float* asm_b    = (const float*)d_in[28];
  const float* rot      = (const float*)d_in[29];
  const float* col_w    = (const float*)d_in[30];
  const float* col_b    = (const float*)d_in[31];
  float* out = (float*)d_out;

  float* ws    = (float*)d_ws;
  float* mask  = ws + OFF_MASK;
  float* fea   = ws + OFF_FEA;
  _Float16* xeh  = (_Float16*)(ws + OFF_XEH);
  _Float16* xenh = (_Float16*)(ws + OFF_XENH);
  _Float16* vsort = (_Float16*)(ws + OFF_VS);
  _Float16* qsort = (_Float16*)(ws + OFF_QS);
  _Float16* ksort = (_Float16*)(ws + OFF_KS);
  _Float16* retb = (_Float16*)(ws + OFF_RET);
  float* bsc   = ws + OFF_BSC;
  int*   ib    = (int*)(ws + OFF_INT);
  int* codes   = ib + IOFF_CODES;
  int* idx     = ib + IOFF_IDX;
  int* undo    = ib + IOFF_UNDO;
  int* hist    = ib + IOFF_HIST;
  int* offs    = ib + IOFF_OFFS;
  float* cay   = ws + OFF_CAY;
  float* cas   = ws + OFF_CAS;
  float* crw   = ws + OFF_CRW;
  float* crb   = ws + OFF_CRB;
  float* xr    = ws + OFF_XR;
  float* feats = ws + OFF_FEATS;
  float* ptmp  = ws + OFF_PTMP;
  float* dwt   = ws + OFF_DWT;
  float* pre1  = ws + OFF_PRE1;

  // ---- phase 1 ----
  k_xr<<<(NB*NL*2)/256, 256, 0, stream>>>(x, spa_dw, spa_db, xr);
  k_wprod<<<16, 256, 0, stream>>>(c11_w, c11_b, res_w, res_b, crw, crb);
  k_s0<<<dim3((NB*NL)/256, 2), 256, 0, stream>>>(xr, s0_pw, s0_dww, s0_dwb, feats);
  k_pw16_all<<<(6*NB*NL2)/256, 256, 0, stream>>>(xr,
      (const float*)d_in[6], (const float*)d_in[9], (const float*)d_in[12], ptmp);
  k_dw_all<<<(6*NB*NCR*NL2)/256, 256, 0, stream>>>(ptmp,
      (const float*)d_in[7], (const float*)d_in[8],
      (const float*)d_in[10], (const float*)d_in[11],
      (const float*)d_in[13], (const float*)d_in[14], dwt);
  k_up_all<<<(6*NB*NCR*NL)/256, 256, 0, stream>>>(dwt, feats);
  k_camean<<<NB*NC, 256, 0, stream>>>(x, cay);
  k_camlp<<<1, 128, 0, stream>>>(cay, ca_w1, ca_b1, ca_w2, ca_b2, cas);
  k_attnmul<<<NB*NL/64, 512, 0, stream>>>(x, feats, fus_w, fus_b, cas, pre1);
  k_mask<<<NB*NL/64, 512, 0, stream>>>(pre1, c11_w, crw, crb, x, mask);

  // ---- phase 2 ----
  (void)hipMemsetAsync(hist, 0, (size_t)NB*NKEY*NTILE*sizeof(int), stream);
  k_xe<<<(NB*NL*2)/256, 256, 0, stream>>>(mask, match_w, match_b, rot, xeh, xenh, codes, hist);
  k_scan<<<NB, 256, 0, stream>>>(hist, offs);
  k_scatter<<<NB*NTILE/4, 256, 0, stream>>>(codes, offs, xeh, xenh, idx, undo, qsort, ksort);
  k_yeh<<<NB*NL/64, 512, 0, stream>>>(mask, asm_w, asm_b, undo, vsort);
  k_attn<<<NB*NHASH*NCHUNKS*2, 512, 0, stream>>>(qsort, ksort, vsort, retb, bsc);
  k_combine<<<(NB*NL)/256, 256, 0, stream>>>(retb, bsc, undo, mask, fea);
  k_collect<<<NB*NL/64, 512, 0, stream>>>(fea, col_w, col_b, x, out);
}

// Round 15
// 317.257 us; speedup vs baseline: 1.0748x; 1.0748x over previous
//
#include <hip/hip_runtime.h>
#include <math.h>

// ---------------- problem constants ----------------
static constexpr int NB = 2;
static constexpr int NC = 64;
static constexpr int NHp = 128, NWp = 128;
static constexpr int NL = NHp * NWp;     // 16384
static constexpr int NCR = 16;
static constexpr int NL2 = 64 * 64;      // 4096
static constexpr int NHASH = 4;
static constexpr int CHUNKSZ = 512;
static constexpr int NCHUNKS = 32;
static constexpr int TOT = NHASH * NL;   // 65536
static constexpr int NKEY = 128;
static constexpr int NTILE = 256;
static constexpr int TILESZ = TOT / NTILE; // 256

typedef _Float16 half4 __attribute__((ext_vector_type(4)));
typedef _Float16 half8 __attribute__((ext_vector_type(8)));
typedef float f32x4 __attribute__((ext_vector_type(4)));

#if __has_builtin(__builtin_amdgcn_exp2f)
  #define EXP2F(x) __builtin_amdgcn_exp2f(x)
#else
  #define EXP2F(x) __expf(0.69314718f*(x))
#endif

// ---------------- workspace layout (float units) ----------------
static constexpr size_t OFF_MASK = 0;
static constexpr size_t OFF_FEA  = OFF_MASK + (size_t)NB*NC*NL;
static constexpr size_t OFF_XE   = OFF_FEA  + (size_t)NB*NC*NL;
static constexpr size_t OFF_XEH  = OFF_XE   + (size_t)NB*NL*NCR;
static constexpr size_t OFF_XENH = OFF_XEH  + (size_t)NB*NL*NCR/2;
static constexpr size_t OFF_VS   = OFF_XENH + (size_t)NB*NL*NCR/2;
static constexpr size_t OFF_RET  = OFF_VS   + (size_t)NB*TOT*NC/2;
static constexpr size_t OFF_BSC  = OFF_RET  + (size_t)NB*TOT*NC/2;
static constexpr size_t OFF_INT  = OFF_BSC  + (size_t)NB*TOT;
static constexpr size_t IOFF_CODES = 0;
static constexpr size_t IOFF_IDX   = IOFF_CODES + (size_t)NB*TOT;
static constexpr size_t IOFF_UNDO  = IOFF_IDX   + (size_t)NB*TOT;
static constexpr size_t IOFF_HIST  = IOFF_UNDO  + (size_t)NB*TOT;
static constexpr size_t IOFF_OFFS  = IOFF_HIST  + (size_t)NB*NKEY*NTILE/2;
static constexpr size_t IOFF_END   = IOFF_OFFS  + (size_t)NB*NKEY*NTILE/2;
static constexpr size_t OFF_CAY = OFF_INT + IOFF_END;
static constexpr size_t OFF_CAS = OFF_CAY + 128;
static constexpr size_t OFF_CRW = OFF_CAS + 128;
static constexpr size_t OFF_CRB = OFF_CRW + 4096;
static constexpr size_t OFF_QS = OFF_FEA;
static constexpr size_t OFF_KS = OFF_QS + (size_t)NB*TOT*NCR/2;
static_assert(OFF_KS + (size_t)NB*TOT*NCR/2 <= OFF_XE, "qs/ks fit in fea region");
static constexpr size_t OFF_PTMP  = OFF_FEA;
static constexpr size_t OFF_DWT   = OFF_PTMP + (size_t)6*NB*NCR*NL2;
static_assert(OFF_DWT + (size_t)6*NB*NCR*NL2 <= OFF_XE, "halfres overlay fits");
static constexpr size_t OFF_XR    = OFF_XE;
static constexpr size_t OFF_FEATS = OFF_XR + (size_t)NB*NCR*NL;
static_assert(OFF_FEATS + (size_t)NB*128*NL <= OFF_RET, "feats overlay fits");
static constexpr size_t OFF_PRE1  = OFF_FEA;

__device__ __forceinline__ float sigmoidf_(float v){ return 1.0f/(1.0f + expf(-v)); }

// ---------------- phase 1 ----------------

__global__ __launch_bounds__(256,4) void k_xr(const float* __restrict__ x,
                     const float* __restrict__ w,
                     const float* __restrict__ b, float* __restrict__ xr){
  int gid = blockIdx.x*256 + threadIdx.x;
  int pix = gid >> 1, hf = gid & 1;
  int bb = pix >> 14, p = pix & (NL-1);
  const float* xi = x + (size_t)bb*NC*NL + (size_t)hf*32*NL + p;
  float acc[16];
  #pragma unroll
  for (int oc=0; oc<16; ++oc) acc[oc] = hf ? 0.f : b[oc];
  for (int ic0=0; ic0<32; ic0+=16){
    float r[16];
    #pragma unroll
    for (int j=0; j<16; ++j) r[j] = xi[(size_t)(ic0+j)*NL];
    #pragma unroll
    for (int oc=0; oc<16; ++oc){
      #pragma unroll
      for (int j=0; j<16; ++j) acc[oc] += r[j]*w[oc*64 + hf*32 + ic0 + j];
    }
  }
  #pragma unroll
  for (int oc=0; oc<16; ++oc) acc[oc] += __shfl_xor(acc[oc], 1, 64);
  if (!hf){
    float* xo = xr + (size_t)bb*NCR*NL + p;
    #pragma unroll
    for (int oc=0; oc<16; ++oc) xo[(size_t)oc*NL] = acc[oc];
  }
}

__global__ __launch_bounds__(256,4) void k_s0(const float* __restrict__ xr,
                     const float* __restrict__ pw,
                     const float* __restrict__ dww, const float* __restrict__ dwb,
                     float* __restrict__ feats){
  int gid = blockIdx.x*256 + threadIdx.x;
  int oc0 = blockIdx.y*16;
  int bb = gid >> 14, p = gid & (NL-1);
  const float* xi = xr + (size_t)bb*NCR*NL + p;
  float r[16];
  #pragma unroll
  for (int ic=0; ic<16; ++ic) r[ic] = xi[(size_t)ic*NL];
  float* fo = feats + (size_t)bb*128*NL + p;
  #pragma unroll
  for (int j=0; j<16; ++j){
    int oc = oc0 + j;
    float s = 0.f;
    #pragma unroll
    for (int ic=0; ic<16; ++ic) s += r[ic]*pw[oc*16+ic];
    fo[(size_t)oc*NL] = s*dww[oc] + dwb[oc];
  }
}

__global__ void k_pw16_all(const float* __restrict__ xr,
                           const float* __restrict__ w0, const float* __restrict__ w1,
                           const float* __restrict__ w2, float* __restrict__ out){
  int gid = blockIdx.x*256 + threadIdx.x;
  if (gid >= 6*NB*NL2) return;
  int p = gid & (NL2-1); int t = gid >> 12; int bb = t & 1; int combo = t >> 1;
  int br = combo >> 1, mode = combo & 1;
  const float* w = (br==0) ? w0 : (br==1) ? w1 : w2;
  int y = p >> 6, x2 = p & 63;
  float r[16];
  #pragma unroll
  for (int ic=0; ic<16; ++ic){
    const float* base = xr + (size_t)(bb*NCR + ic)*NL + (size_t)(2*y)*NWp + 2*x2;
    float a = base[0], b_ = base[1], c_ = base[NWp], d = base[NWp+1];
    r[ic] = mode ? 0.25f*(a+b_+c_+d) : fmaxf(fmaxf(a,b_), fmaxf(c_,d));
  }
  float* oo = out + ((size_t)(combo*NB + bb)*NCR)*NL2 + p;
  #pragma unroll
  for (int oc=0; oc<16; ++oc){
    float s = 0.f;
    #pragma unroll
    for (int ic=0; ic<16; ++ic) s += r[ic]*w[oc*16+ic];
    oo[(size_t)oc*NL2] = s;
  }
}

__global__ void k_dw_all(const float* __restrict__ in,
                         const float* __restrict__ w3, const float* __restrict__ b3,
                         const float* __restrict__ w5, const float* __restrict__ b5,
                         const float* __restrict__ w7, const float* __restrict__ b7,
                         float* __restrict__ out){
  int gid = blockIdx.x*256 + threadIdx.x;
  if (gid >= 6*NB*NCR*NL2) return;
  int p = gid & (NL2-1); int t = gid >> 12; int c = t & 15; int r2 = t >> 4;
  int bb = r2 & 1; int combo = r2 >> 1;
  int br = combo >> 1;
  int K = (br==0) ? 3 : (br==1) ? 5 : 7; int P = K >> 1;
  const float* w = (br==0) ? w3 : (br==1) ? w5 : w7;
  const float* bias = (br==0) ? b3 : (br==1) ? b5 : b7;
  int y = p >> 6, x = p & 63;
  const float* xi = in + ((size_t)(combo*NB + bb)*NCR + c)*NL2;
  float s = bias[c];
  for (int dy=0; dy<K; ++dy){
    int iy = y + dy - P;
    if ((unsigned)iy < 64u){
      for (int dx=0; dx<K; ++dx){
        int ix = x + dx - P;
        if ((unsigned)ix < 64u) s += xi[iy*64 + ix] * w[(c*K + dy)*K + dx];
      }
    }
  }
  out[gid] = s;
}

__global__ void k_up_all(const float* __restrict__ in, float* __restrict__ feats){
  int gid = blockIdx.x*256 + threadIdx.x;
  if (gid >= 6*NB*NCR*NL) return;
  int p = gid & (NL-1); int t = gid >> 14; int c = t & 15; int r2 = t >> 4;
  int bb = r2 & 1; int combo = r2 >> 1;
  int y = p >> 7, x = p & 127;
  const float sc = 63.0f/127.0f;
  float fy = y*sc; int ly = (int)floorf(fy); int hy = min(ly+1, 63); fy -= (float)ly;
  float fx = x*sc; int lx = (int)floorf(fx); int hx = min(lx+1, 63); float gx = fx - (float)lx;
  const float* xi = in + ((size_t)(combo*NB + bb)*NCR + c)*NL2;
  float v0 = xi[ly*64+lx]*(1.f-fy) + xi[hy*64+lx]*fy;
  float v1 = xi[ly*64+hx]*(1.f-fy) + xi[hy*64+hx]*fy;
  int coff = 32 + combo*16 + c;
  feats[(size_t)bb*128*NL + (size_t)coff*NL + p] = v0*(1.f-gx) + v1*gx;
}

__global__ void k_camean(const float* __restrict__ x, float* __restrict__ cay){
  __shared__ float red[256];
  int bc = blockIdx.x; int tid = threadIdx.x;
  float s = 0.f;
  for (int i = tid; i < NL; i += 256) s += x[(size_t)bc*NL + i];
  red[tid] = s; __syncthreads();
  for (int st=128; st>0; st>>=1){ if (tid<st) red[tid]+=red[tid+st]; __syncthreads(); }
  if (tid==0) cay[bc] = red[0] / (float)NL;
}

__global__ void k_camlp(const float* __restrict__ cay,
                        const float* __restrict__ w1, const float* __restrict__ b1,
                        const float* __restrict__ w2, const float* __restrict__ b2,
                        float* __restrict__ cas){
  __shared__ float z[NB*4];
  int tid = threadIdx.x;
  if (tid < NB*4){
    int bb = tid >> 2, j = tid & 3;
    float s = b1[j];
    for (int ic=0; ic<NC; ++ic) s += cay[bb*NC+ic]*w1[j*NC+ic];
    z[tid] = fmaxf(s, 0.f);
  }
  __syncthreads();
  if (tid < NB*NC){
    int bb = tid >> 6, oc = tid & 63;
    float s = b2[oc];
    #pragma unroll
    for (int j=0; j<4; ++j) s += z[bb*4+j]*w2[oc*4+j];
    cas[tid] = sigmoidf_(s);
  }
}

__global__ void k_wprod(const float* __restrict__ c11w, const float* __restrict__ c11b,
                        const float* __restrict__ rw, const float* __restrict__ rb,
                        float* __restrict__ crw, float* __restrict__ crb){
  int gid = blockIdx.x*256 + threadIdx.x;
  if (gid >= 4096) return;
  int o = gid >> 6, i = gid & 63;
  float s = 0.f;
  for (int k=0; k<64; ++k) s += c11w[o*64+k]*rw[k*64+i];
  crw[gid] = s;
  if (i == 0){
    float t = c11b[o];
    for (int k=0; k<64; ++k) t += c11w[o*64+k]*rb[k];
    crb[o] = t;
  }
}

__global__ __launch_bounds__(256,4) void k_attnmul(const float* __restrict__ x,
                          const float* __restrict__ feats,
                          const float* __restrict__ fw, const float* __restrict__ fb,
                          const float* __restrict__ cas, float* __restrict__ pre1){
  int gid = blockIdx.x*256 + threadIdx.x;
  int oc0 = blockIdx.y*16;
  int bb = gid >> 14, p = gid & (NL-1);
  const float* fi = feats + (size_t)bb*128*NL + p;
  float acc[16];
  #pragma unroll
  for (int j=0; j<16; ++j) acc[j] = fb[oc0+j];
  for (int k0=0; k0<128; k0+=8){
    float fr[8];
    #pragma unroll
    for (int j=0; j<8; ++j) fr[j] = fi[(size_t)(k0+j)*NL];
    #pragma unroll
    for (int j=0; j<16; ++j){
      #pragma unroll
      for (int t=0; t<8; ++t) acc[j] += fr[t]*fw[(oc0+j)*128+k0+t];
    }
  }
  const float* xb = x + (size_t)bb*NC*NL + p;
  float* po = pre1 + (size_t)bb*NC*NL + p;
  #pragma unroll
  for (int j=0; j<16; ++j){
    int oc = oc0 + j;
    float xv = xb[(size_t)oc*NL];
    po[(size_t)oc*NL] = xv*(sigmoidf_(acc[j]) + cas[bb*64+oc]);
  }
}

__global__ __launch_bounds__(256,4) void k_mask(const float* __restrict__ pre1,
                       const float* __restrict__ c11w,
                       const float* __restrict__ crw, const float* __restrict__ crb,
                       const float* __restrict__ x, float* __restrict__ mask){
  int gid = blockIdx.x*256 + threadIdx.x;
  int oc0 = blockIdx.y*16;
  int bb = gid >> 14, p = gid & (NL-1);
  const float* pi = pre1 + (size_t)bb*NC*NL + p;
  const float* xi = x + (size_t)bb*NC*NL + p;
  float acc[16];
  #pragma unroll
  for (int j=0; j<16; ++j) acc[j] = crb[oc0+j];
  for (int ic0=0; ic0<64; ic0+=8){
    float pr[8], xr8[8];
    #pragma unroll
    for (int j=0; j<8; ++j){ pr[j] = pi[(size_t)(ic0+j)*NL]; xr8[j] = xi[(size_t)(ic0+j)*NL]; }
    #pragma unroll
    for (int j=0; j<16; ++j){
      #pragma unroll
      for (int t=0; t<8; ++t)
        acc[j] += pr[t]*c11w[(oc0+j)*64+ic0+t] + xr8[t]*crw[(oc0+j)*64+ic0+t];
    }
  }
  float* mo = mask + (size_t)bb*NC*NL + p;
  #pragma unroll
  for (int j=0; j<16; ++j){
    int oc = oc0 + j;
    mo[(size_t)oc*NL] = acc[j] + xi[(size_t)oc*NL];
  }
}

// ---------------- phase 2 ----------------

__global__ __launch_bounds__(256,4) void k_xe(const float* __restrict__ mask,
                     const float* __restrict__ w, const float* __restrict__ b,
                     const float* __restrict__ rot,
                     _Float16* __restrict__ xeh, _Float16* __restrict__ xenh,
                     int* __restrict__ codes, int* __restrict__ hist){
  int gid = blockIdx.x*256 + threadIdx.x;
  int pix = gid >> 1, hf = gid & 1;
  int bb = pix >> 14, l = pix & (NL-1);
  const float* mi = mask + (size_t)bb*NC*NL + (size_t)hf*32*NL + l;
  float acc[16];
  #pragma unroll
  for (int oc=0; oc<16; ++oc) acc[oc] = hf ? 0.f : b[oc];
  for (int ic0=0; ic0<32; ic0+=16){
    float r[16];
    #pragma unroll
    for (int j=0; j<16; ++j) r[j] = mi[(size_t)(ic0+j)*NL];
    #pragma unroll
    for (int oc=0; oc<16; ++oc){
      #pragma unroll
      for (int j=0; j<16; ++j) acc[oc] += r[j]*w[oc*64 + hf*32 + ic0 + j];
    }
  }
  #pragma unroll
  for (int oc=0; oc<16; ++oc) acc[oc] += __shfl_xor(acc[oc], 1, 64);
  if (!hf){
    float n2 = 0.f;
    #pragma unroll
    for (int oc=0; oc<16; ++oc) n2 += acc[oc]*acc[oc];
    float inv = 1.0f / fmaxf(sqrtf(n2), 5e-5f);
    _Float16* ho = xeh + (size_t)pix*NCR;
    _Float16* no = xenh + (size_t)pix*NCR;
    #pragma unroll
    for (int g=0; g<4; ++g){
      half4 hv, nv;
      #pragma unroll
      for (int j=0; j<4; ++j){ hv[j] = (_Float16)acc[g*4+j]; nv[j] = (_Float16)(acc[g*4+j]*inv); }
      *(half4*)(ho + g*4) = hv;
      *(half4*)(no + g*4) = nv;
    }
  }
  #pragma unroll
  for (int hh=0; hh<2; ++hh){
    int h = hf*2 + hh;
    float rv[16];
    #pragma unroll
    for (int i=0; i<16; ++i){
      float s = 0.f;
      #pragma unroll
      for (int f=0; f<16; ++f) s += acc[f]*rot[(f*NHASH + h)*16 + i];
      rv[i] = s;
    }
    float best = -1e30f; int bi = 0;
    #pragma unroll
    for (int i=0; i<16; ++i){ if (rv[i] > best){ best = rv[i]; bi = i; } }
    #pragma unroll
    for (int i=0; i<16; ++i){ float val = -rv[i]; if (val > best){ best = val; bi = 16+i; } }
    int code = bi + h*32;
    codes[((bb*NHASH + h) << 14) + l] = code;
    int tile = h*64 + (l >> 8);
    atomicAdd(&hist[bb*NKEY*NTILE + code*NTILE + tile], 1);
  }
}

__global__ __launch_bounds__(256,4) void k_yeh(const float* __restrict__ mask,
                      const float* __restrict__ w, const float* __restrict__ b,
                      const int* __restrict__ undo, _Float16* __restrict__ vs){
  int gid = blockIdx.x*256 + threadIdx.x;
  int oc0 = blockIdx.y*16;
  int bb = gid >> 14, l = gid & (NL-1);
  const float* mi = mask + (size_t)bb*NC*NL + l;
  float acc[16];
  #pragma unroll
  for (int j=0; j<16; ++j) acc[j] = b[oc0+j];
  for (int ic0=0; ic0<64; ic0+=8){
    float r[8];
    #pragma unroll
    for (int j=0; j<8; ++j) r[j] = mi[(size_t)(ic0+j)*NL];
    #pragma unroll
    for (int j=0; j<16; ++j){
      #pragma unroll
      for (int t=0; t<8; ++t) acc[j] += r[t]*w[(oc0+j)*64+ic0+t];
    }
  }
  half8 h0, h1;
  #pragma unroll
  for (int j=0; j<8; ++j){ h0[j] = (_Float16)acc[j]; h1[j] = (_Float16)acc[8+j]; }
  const int* ub = undo + bb*TOT;
  #pragma unroll
  for (int h=0; h<4; ++h){
    int pos = ub[h*NL + l];
    _Float16* vo = vs + ((size_t)bb*TOT + pos)*64 + oc0;
    *(half8*)(vo) = h0;
    *(half8*)(vo + 8) = h1;
  }
}

__global__ void k_scan(const int* __restrict__ hist, int* __restrict__ offs){
  __shared__ int part[256];
  int bb = blockIdx.x; int t = threadIdx.x;
  const int* hi = hist + (size_t)bb*NKEY*NTILE;
  int* oo = offs + (size_t)bb*NKEY*NTILE;
  int s = 0;
  for (int i=0; i<128; ++i) s += hi[t*128 + i];
  part[t] = s; __syncthreads();
  int v = s;
  for (int off=1; off<256; off<<=1){
    int u = (t >= off) ? part[t-off] : 0;
    __syncthreads();
    v += u; part[t] = v;
    __syncthreads();
  }
  int run = v - s;
  for (int i=0; i<128; ++i){ int q = hi[t*128+i]; oo[t*128+i] = run; run += q; }
}

__global__ __launch_bounds__(256) void k_scatter(const int* __restrict__ codes,
                          const int* __restrict__ offs,
                          const _Float16* __restrict__ xeh, const _Float16* __restrict__ xenh,
                          int* __restrict__ undo,
                          _Float16* __restrict__ qs, _Float16* __restrict__ ks){
  __shared__ int cnt[4][NKEY];
  int wid = threadIdx.x >> 6, lane = threadIdx.x & 63;
  int t4 = blockIdx.x;
  int bb = t4 >> 6;
  int tile = (t4 & 63)*4 + wid;
  cnt[wid][lane] = 0; cnt[wid][64+lane] = 0;
  const int* cb = codes + bb*TOT;
  const int* ob = offs + (size_t)bb*NKEY*NTILE;
  int* ub = undo + bb*TOT;
  for (int g=0; g<4; ++g){
    int j = tile*TILESZ + g*64 + lane;
    int k = cb[j];
    unsigned long long m = ~0ull;
    #pragma unroll
    for (int bit=0; bit<7; ++bit){
      unsigned long long bmask = __ballot((k >> bit) & 1);
      m &= ((k >> bit) & 1) ? bmask : ~bmask;
    }
    int rank = __popcll(m & ((1ull << lane) - 1ull));
    int leader = __ffsll((unsigned long long)m) - 1;
    int base = 0;
    if (lane == leader){
      base = cnt[wid][k];
      cnt[wid][k] = base + __popcll(m);
    }
    base = __shfl(base, leader, 64);
    int pos = ob[k*NTILE + tile] + base + rank;
    ub[j] = pos;
    int l = j & (NL-1);
    const _Float16* qp = xeh + ((size_t)bb*NL + l)*16;
    const _Float16* kp = xenh + ((size_t)bb*NL + l)*16;
    _Float16* qo = qs + ((size_t)bb*TOT + pos)*16;
    _Float16* ko = ks + ((size_t)bb*TOT + pos)*16;
    *(half8*)(qo)     = *(const half8*)(qp);
    *(half8*)(qo + 8) = *(const half8*)(qp + 8);
    *(half8*)(ko)     = *(const half8*)(kp);
    *(half8*)(ko + 8) = *(const half8*)(kp + 8);
    __threadfence_block();
  }
}

// MFMA flash attention: sorted operands, T14 prefetch, native-exp2 softmax,
// permuted V^T layout so each PV A-fragment is ONE b128 LDS read.
__global__ __launch_bounds__(512) void k_attn(
    const _Float16* __restrict__ qs, const _Float16* __restrict__ ks,
    const _Float16* __restrict__ vs,
    _Float16* __restrict__ retb, float* __restrict__ bsc){
  __shared__ _Float16 kt[64*20];
  __shared__ _Float16 vt[64*72];   // [c][64 permuted keys], stride 72 (16B aligned)
  int blk = blockIdx.x;
  int qh = blk & 1; int kk = (blk >> 1) & 31; int h = (blk >> 6) & 3; int bb = blk >> 8;
  int tid = threadIdx.x;
  int w = tid >> 6, lane = tid & 63, col = lane & 15, grp = lane >> 4;
  int qbase = h*NL + kk*CHUNKSZ + qh*256 + w*32;

  half4 qfr[2]; int posq[2];
  #pragma unroll
  for (int qf=0; qf<2; ++qf){
    posq[qf] = qbase + qf*16 + col;
    qfr[qf] = *(const half4*)(qs + ((size_t)bb*TOT + posq[qf])*16 + grp*4);
    #pragma unroll
    for (int i=0; i<4; ++i) qfr[qf][i] = (_Float16)((float)qfr[qf][i] * 1.44269504f);
  }

  f32x4 O[4][2];
  #pragma unroll
  for (int a=0; a<4; ++a)
    #pragma unroll
    for (int b=0; b<2; ++b) O[a][b] = (f32x4){0.f,0.f,0.f,0.f};
  float m_[2] = {-1e30f,-1e30f};
  float ssum[2] = {0.f,0.f};

  int kx = tid & 63, c0 = (tid >> 6) * 8;
  // permuted column: within each 32-block, key k -> slot ((k&12)<<1)+((k&16)>>2)+(k&3)
  int kxl = kx & 31;
  int vcol = (kx & 32) + (((kxl & 12) << 1) + ((kxl & 16) >> 2) + (kxl & 3));
  int kr = tid >> 1, khf = tid & 1;

  #define SPOS(jj) ({ int sec_ = (jj) >> 9; int j0_ = (jj) & 511; \
      int cc_ = kk + ((sec_==1) ? -1 : (sec_==2) ? 1 : 0); \
      cc_ = (cc_ + NCHUNKS) & (NCHUNKS-1); h*NL + cc_*CHUNKSZ + j0_; })

  half8 vv = *(const half8*)(vs + ((size_t)bb*TOT + SPOS(kx))*64 + c0);
  half8 kv;
  if (tid < 128) kv = *(const half8*)(ks + ((size_t)bb*TOT + SPOS(kr))*16 + khf*8);

  for (int t=0; t<24; ++t){
    __syncthreads();
    #pragma unroll
    for (int j=0; j<8; ++j) vt[(c0+j)*72 + vcol] = vv[j];
    if (tid < 128) *(half8*)(kt + kr*20 + khf*8) = kv;
    __syncthreads();
    if (t+1 < 24){
      int jj = (t+1)*64;
      vv = *(const half8*)(vs + ((size_t)bb*TOT + SPOS(jj + kx))*64 + c0);
      if (tid < 128) kv = *(const half8*)(ks + ((size_t)bb*TOT + SPOS(jj + kr))*16 + khf*8);
    }

    f32x4 S[4][2];
    #pragma unroll
    for (int kb=0; kb<4; ++kb){
      half4 ka = *(const half4*)(kt + (kb*16 + col)*20 + grp*4);
      #pragma unroll
      for (int qf=0; qf<2; ++qf)
        S[kb][qf] = __builtin_amdgcn_mfma_f32_16x16x16f16(
            ka, qfr[qf], (f32x4){0.f,0.f,0.f,0.f}, 0, 0, 0);
    }

    half8 pb[2][2];
    #pragma unroll
    for (int qf=0; qf<2; ++qf){
      float mtl = -1e30f;
      #pragma unroll
      for (int kb=0; kb<4; ++kb)
        #pragma unroll
        for (int i=0; i<4; ++i) mtl = fmaxf(mtl, S[kb][qf][i]);
      if (__any(mtl > m_[qf] + 11.5f)){
        float mt = fmaxf(mtl, __shfl_xor(mtl, 16, 64));
        mt = fmaxf(mt, __shfl_xor(mt, 32, 64));
        float mn = fmaxf(m_[qf], mt);
        float sc = EXP2F(m_[qf] - mn);
        ssum[qf] *= sc;
        m_[qf] = mn;
        #pragma unroll
        for (int cf=0; cf<4; ++cf)
          #pragma unroll
          for (int i=0; i<4; ++i) O[cf][qf][i] *= sc;
      }
      float ps = 0.f;
      #pragma unroll
      for (int k2=0; k2<2; ++k2){
        half8 hb;
        #pragma unroll
        for (int i=0; i<4; ++i){
          float p0 = EXP2F(S[2*k2][qf][i]   - m_[qf]);
          float p1 = EXP2F(S[2*k2+1][qf][i] - m_[qf]);
          ps += p0 + p1;
          hb[i]   = (_Float16)p0;
          hb[4+i] = (_Float16)p1;
        }
        pb[qf][k2] = hb;
      }
      ssum[qf] += ps;
    }

    // PV 16x16x32: A-fragment = single b128 from permuted vt
    #pragma unroll
    for (int cf=0; cf<4; ++cf){
      #pragma unroll
      for (int k2=0; k2<2; ++k2){
        half8 va = *(const half8*)(vt + (cf*16 + col)*72 + k2*32 + grp*8);
        #pragma unroll
        for (int qf=0; qf<2; ++qf)
          O[cf][qf] = __builtin_amdgcn_mfma_f32_16x16x32_f16(
              va, pb[qf][k2], O[cf][qf], 0, 0, 0);
      }
    }
  }
  #undef SPOS

  #pragma unroll
  for (int qf=0; qf<2; ++qf){
    float st = ssum[qf];
    st += __shfl_xor(st, 16, 64);
    st += __shfl_xor(st, 32, 64);
    float inv = 1.0f/st;
    size_t rb = ((size_t)bb*TOT + posq[qf])*64;
    #pragma unroll
    for (int cf=0; cf<4; ++cf){
      half4 o;
      #pragma unroll
      for (int i=0; i<4; ++i) o[i] = (_Float16)(O[cf][qf][i]*inv);
      *(half4*)(retb + rb + cf*16 + grp*4) = o;
    }
    if (grp == 0) bsc[(size_t)bb*TOT + posq[qf]] = m_[qf]*0.69314718f + logf(st);
  }
}

__global__ __launch_bounds__(256,4) void k_combine(const _Float16* __restrict__ retb,
                          const float* __restrict__ bsc,
                          const int* __restrict__ undo, const float* __restrict__ mask,
                          float* __restrict__ fea){
  int gid = blockIdx.x*256 + threadIdx.x;
  int c0 = blockIdx.y*32;
  int bb = gid >> 14; int l = gid & (NL-1);
  const int* ub = undo + bb*TOT;
  int pos[4]; float sc[4];
  #pragma unroll
  for (int h=0; h<4; ++h){ pos[h] = ub[h*NL + l]; sc[h] = bsc[bb*TOT + pos[h]]; }
  float mx = fmaxf(fmaxf(sc[0],sc[1]), fmaxf(sc[2],sc[3]));
  float e[4]; float tot = 0.f;
  #pragma unroll
  for (int h=0; h<4; ++h){ e[h] = __expf(sc[h]-mx); tot += e[h]; }
  float inv = 0.1f/tot;
  const float* mb_ = mask + (size_t)bb*NC*NL + l;
  float* fo = fea + (size_t)bb*NC*NL + l;
  const _Float16* r0 = retb + ((size_t)bb*TOT + pos[0])*NC + c0;
  const _Float16* r1 = retb + ((size_t)bb*TOT + pos[1])*NC + c0;
  const _Float16* r2 = retb + ((size_t)bb*TOT + pos[2])*NC + c0;
  const _Float16* r3 = retb + ((size_t)bb*TOT + pos[3])*NC + c0;
  #pragma unroll
  for (int g=0; g<4; ++g){
    half8 v0 = *(const half8*)(r0 + g*8);
    half8 v1 = *(const half8*)(r1 + g*8);
    half8 v2 = *(const half8*)(r2 + g*8);
    half8 v3 = *(const half8*)(r3 + g*8);
    #pragma unroll
    for (int j=0; j<8; ++j){
      int c = c0 + g*8 + j;
      float v = (float)v0[j]*e[0] + (float)v1[j]*e[1] + (float)v2[j]*e[2] + (float)v3[j]*e[3];
      fo[(size_t)c*NL] = v*inv + mb_[(size_t)c*NL];
    }
  }
}

__global__ __launch_bounds__(256,4) void k_collect(const float* __restrict__ fea,
                          const float* __restrict__ w,
                          const float* __restrict__ b, const float* __restrict__ x,
                          float* __restrict__ out){
  int gid = blockIdx.x*256 + threadIdx.x;
  int oc0 = blockIdx.y*16;
  int bb = gid >> 14, p = gid & (NL-1);
  const float* fi = fea + (size_t)bb*NC*NL + p;
  const float* xi = x + (size_t)bb*NC*NL + p;
  float acc[16];
  #pragma unroll
  for (int j=0; j<16; ++j) acc[j] = b[oc0+j];
  for (int ic0=0; ic0<64; ic0+=8){
    float r[8];
    #pragma unroll
    for (int j=0; j<8; ++j) r[j] = fi[(size_t)(ic0+j)*NL];
    #pragma unroll
    for (int j=0; j<16; ++j){
      #pragma unroll
      for (int t=0; t<8; ++t) acc[j] += r[t]*w[(oc0+j)*64+ic0+t];
    }
  }
  float* oo = out + (size_t)bb*NC*NL + p;
  #pragma unroll
  for (int j=0; j<16; ++j){
    int oc = oc0 + j;
    oo[(size_t)oc*NL] = acc[j] + xi[(size_t)oc*NL];
  }
}

// ---------------- launcher ----------------
extern "C" void kernel_launch(void* const* d_in, const int* in_sizes, int n_in,
                              void* d_out, int out_size, void* d_ws, size_t ws_size,
                              hipStream_t stream) {
  const float* x        = (const float*)d_in[0];
  const float* spa_dw   = (const float*)d_in[1];
  const float* spa_db   = (const float*)d_in[2];
  const float* s0_pw    = (const float*)d_in[3];
  const float* s0_dww   = (const float*)d_in[4];
  const float* s0_dwb   = (const float*)d_in[5];
  const float* fus_w    = (const float*)d_in[15];
  const float* fus_b    = (const float*)d_in[16];
  const float* res_w    = (const float*)d_in[17];
  const float* res_b    = (const float*)d_in[18];
  const float* ca_w1    = (const float*)d_in[19];
  const float* ca_b1    = (const float*)d_in[20];
  const float* ca_w2    = (const float*)d_in[21];
  const float* ca_b2    = (const float*)d_in[22];
  const float* c11_w    = (const float*)d_in[23];
  const float* c11_b    = (const float*)d_in[24];
  const float* match_w  = (const float*)d_in[25];
  const float* match_b  = (const float*)d_in[26];
  const float* asm_w    = (const float*)d_in[27];
  const float* asm_b    = (const float*)d_in[28];
  const float* rot      = (const float*)d_in[29];
  const float* col_w    = (const float*)d_in[30];
  const float* col_b    = (const float*)d_in[31];
  float* out = (float*)d_out;

  float* ws    = (float*)d_ws;
  float* mask  = ws + OFF_MASK;
  float* fea   = ws + OFF_FEA;
  _Float16* xeh  = (_Float16*)(ws + OFF_XEH);
  _Float16* xenh = (_Float16*)(ws + OFF_XENH);
  _Float16* vsort = (_Float16*)(ws + OFF_VS);
  _Float16* qsort = (_Float16*)(ws + OFF_QS);
  _Float16* ksort = (_Float16*)(ws + OFF_KS);
  _Float16* retb = (_Float16*)(ws + OFF_RET);
  float* bsc   = ws + OFF_BSC;
  int*   ib    = (int*)(ws + OFF_INT);
  int* codes   = ib + IOFF_CODES;
  int* undo    = ib + IOFF_UNDO;
  int* hist    = ib + IOFF_HIST;
  int* offs    = ib + IOFF_OFFS;
  float* cay   = ws + OFF_CAY;
  float* cas   = ws + OFF_CAS;
  float* crw   = ws + OFF_CRW;
  float* crb   = ws + OFF_CRB;
  float* xr    = ws + OFF_XR;
  float* feats = ws + OFF_FEATS;
  float* ptmp  = ws + OFF_PTMP;
  float* dwt   = ws + OFF_DWT;
  float* pre1  = ws + OFF_PRE1;

  // ---- phase 1 ----
  k_xr<<<(NB*NL*2)/256, 256, 0, stream>>>(x, spa_dw, spa_db, xr);
  k_wprod<<<16, 256, 0, stream>>>(c11_w, c11_b, res_w, res_b, crw, crb);
  k_s0<<<dim3((NB*NL)/256, 2), 256, 0, stream>>>(xr, s0_pw, s0_dww, s0_dwb, feats);
  k_pw16_all<<<(6*NB*NL2)/256, 256, 0, stream>>>(xr,
      (const float*)d_in[6], (const float*)d_in[9], (const float*)d_in[12], ptmp);
  k_dw_all<<<(6*NB*NCR*NL2)/256, 256, 0, stream>>>(ptmp,
      (const float*)d_in[7], (const float*)d_in[8],
      (const float*)d_in[10], (const float*)d_in[11],
      (const float*)d_in[13], (const float*)d_in[14], dwt);
  k_up_all<<<(6*NB*NCR*NL)/256, 256, 0, stream>>>(dwt, feats);
  k_camean<<<NB*NC, 256, 0, stream>>>(x, cay);
  k_camlp<<<1, 128, 0, stream>>>(cay, ca_w1, ca_b1, ca_w2, ca_b2, cas);
  k_attnmul<<<dim3((NB*NL)/256, 4), 256, 0, stream>>>(x, feats, fus_w, fus_b, cas, pre1);
  k_mask<<<dim3((NB*NL)/256, 4), 256, 0, stream>>>(pre1, c11_w, crw, crb, x, mask);

  // ---- phase 2 ----
  (void)hipMemsetAsync(hist, 0, (size_t)NB*NKEY*NTILE*sizeof(int), stream);
  k_xe<<<(NB*NL*2)/256, 256, 0, stream>>>(mask, match_w, match_b, rot, xeh, xenh, codes, hist);
  k_scan<<<NB, 256, 0, stream>>>(hist, offs);
  k_scatter<<<NB*NTILE/4, 256, 0, stream>>>(codes, offs, xeh, xenh, undo, qsort, ksort);
  k_yeh<<<dim3((NB*NL)/256, 4), 256, 0, stream>>>(mask, asm_w, asm_b, undo, vsort);
  k_attn<<<NB*NHASH*NCHUNKS*2, 512, 0, stream>>>(qsort, ksort, vsort, retb, bsc);
  k_combine<<<dim3((NB*NL)/256, 2), 256, 0, stream>>>(retb, bsc, undo, mask, fea);
  k_collect<<<dim3((NB*NL)/256, 4), 256, 0, stream>>>(fea, col_w, col_b, x, out);
}

// Round 16
// 316.729 us; speedup vs baseline: 1.0766x; 1.0017x over previous
//
#include <hip/hip_runtime.h>
#include <math.h>

// ---------------- problem constants ----------------
static constexpr int NB = 2;
static constexpr int NC = 64;
static constexpr int NHp = 128, NWp = 128;
static constexpr int NL = NHp * NWp;     // 16384
static constexpr int NCR = 16;
static constexpr int NL2 = 64 * 64;      // 4096
static constexpr int NHASH = 4;
static constexpr int CHUNKSZ = 512;
static constexpr int NCHUNKS = 32;
static constexpr int TOT = NHASH * NL;   // 65536
static constexpr int NKEY = 128;
static constexpr int NTILE = 256;
static constexpr int TILESZ = TOT / NTILE; // 256

typedef _Float16 half4 __attribute__((ext_vector_type(4)));
typedef _Float16 half8 __attribute__((ext_vector_type(8)));
typedef float f32x4 __attribute__((ext_vector_type(4)));

#if __has_builtin(__builtin_amdgcn_exp2f)
  #define EXP2F(x) __builtin_amdgcn_exp2f(x)
#else
  #define EXP2F(x) __expf(0.69314718f*(x))
#endif

// ---------------- workspace layout (float units) ----------------
static constexpr size_t OFF_MASK = 0;
static constexpr size_t OFF_FEA  = OFF_MASK + (size_t)NB*NC*NL;
static constexpr size_t OFF_XE   = OFF_FEA  + (size_t)NB*NC*NL;
static constexpr size_t OFF_XEH  = OFF_XE   + (size_t)NB*NL*NCR;
static constexpr size_t OFF_XENH = OFF_XEH  + (size_t)NB*NL*NCR/2;
static constexpr size_t OFF_VS   = OFF_XENH + (size_t)NB*NL*NCR/2;
static constexpr size_t OFF_RET  = OFF_VS   + (size_t)NB*TOT*NC/2;
static constexpr size_t OFF_BSC  = OFF_RET  + (size_t)NB*TOT*NC/2;
static constexpr size_t OFF_INT  = OFF_BSC  + (size_t)NB*TOT;
static constexpr size_t IOFF_CODES = 0;
static constexpr size_t IOFF_IDX   = IOFF_CODES + (size_t)NB*TOT;
static constexpr size_t IOFF_UNDO  = IOFF_IDX   + (size_t)NB*TOT;
static constexpr size_t IOFF_HIST  = IOFF_UNDO  + (size_t)NB*TOT;
static constexpr size_t IOFF_OFFS  = IOFF_HIST  + (size_t)NB*NKEY*NTILE/2;
static constexpr size_t IOFF_END   = IOFF_OFFS  + (size_t)NB*NKEY*NTILE/2;
static constexpr size_t OFF_CAY = OFF_INT + IOFF_END;
static constexpr size_t OFF_CAS = OFF_CAY + 128;
static constexpr size_t OFF_CRW = OFF_CAS + 128;
static constexpr size_t OFF_CRB = OFF_CRW + 4096;
static constexpr size_t OFF_QS = OFF_FEA;
static constexpr size_t OFF_KS = OFF_QS + (size_t)NB*TOT*NCR/2;
static_assert(OFF_KS + (size_t)NB*TOT*NCR/2 <= OFF_XE, "qs/ks fit in fea region");
static constexpr size_t OFF_PTMP  = OFF_FEA;
static constexpr size_t OFF_DWT   = OFF_PTMP + (size_t)6*NB*NCR*NL2;
static_assert(OFF_DWT + (size_t)6*NB*NCR*NL2 <= OFF_XE, "halfres overlay fits");
static constexpr size_t OFF_XR    = OFF_XE;
static constexpr size_t OFF_FEATS = OFF_XR + (size_t)NB*NCR*NL;
static_assert(OFF_FEATS + (size_t)NB*128*NL <= OFF_RET, "feats overlay fits");
static constexpr size_t OFF_PRE1  = OFF_FEA;

__device__ __forceinline__ float sigmoidf_(float v){ return 1.0f/(1.0f + expf(-v)); }

// ---------------- phase 1 ----------------

__global__ __launch_bounds__(256,4) void k_xr(const float* __restrict__ x,
                     const float* __restrict__ w,
                     const float* __restrict__ b, float* __restrict__ xr){
  int gid = blockIdx.x*256 + threadIdx.x;
  int pix = gid >> 1, hf = gid & 1;
  int bb = pix >> 14, p = pix & (NL-1);
  const float* xi = x + (size_t)bb*NC*NL + (size_t)hf*32*NL + p;
  float acc[16];
  #pragma unroll
  for (int oc=0; oc<16; ++oc) acc[oc] = hf ? 0.f : b[oc];
  for (int ic0=0; ic0<32; ic0+=16){
    float r[16];
    #pragma unroll
    for (int j=0; j<16; ++j) r[j] = xi[(size_t)(ic0+j)*NL];
    #pragma unroll
    for (int oc=0; oc<16; ++oc){
      #pragma unroll
      for (int j=0; j<16; ++j) acc[oc] += r[j]*w[oc*64 + hf*32 + ic0 + j];
    }
  }
  #pragma unroll
  for (int oc=0; oc<16; ++oc) acc[oc] += __shfl_xor(acc[oc], 1, 64);
  if (!hf){
    float* xo = xr + (size_t)bb*NCR*NL + p;
    #pragma unroll
    for (int oc=0; oc<16; ++oc) xo[(size_t)oc*NL] = acc[oc];
  }
}

__global__ __launch_bounds__(256,4) void k_s0(const float* __restrict__ xr,
                     const float* __restrict__ pw,
                     const float* __restrict__ dww, const float* __restrict__ dwb,
                     float* __restrict__ feats){
  int gid = blockIdx.x*256 + threadIdx.x;
  int oc0 = blockIdx.y*16;
  int bb = gid >> 14, p = gid & (NL-1);
  const float* xi = xr + (size_t)bb*NCR*NL + p;
  float r[16];
  #pragma unroll
  for (int ic=0; ic<16; ++ic) r[ic] = xi[(size_t)ic*NL];
  float* fo = feats + (size_t)bb*128*NL + p;
  #pragma unroll
  for (int j=0; j<16; ++j){
    int oc = oc0 + j;
    float s = 0.f;
    #pragma unroll
    for (int ic=0; ic<16; ++ic) s += r[ic]*pw[oc*16+ic];
    fo[(size_t)oc*NL] = s*dww[oc] + dwb[oc];
  }
}

__global__ void k_pw16_all(const float* __restrict__ xr,
                           const float* __restrict__ w0, const float* __restrict__ w1,
                           const float* __restrict__ w2, float* __restrict__ out){
  int gid = blockIdx.x*256 + threadIdx.x;
  if (gid >= 6*NB*NL2) return;
  int p = gid & (NL2-1); int t = gid >> 12; int bb = t & 1; int combo = t >> 1;
  int br = combo >> 1, mode = combo & 1;
  const float* w = (br==0) ? w0 : (br==1) ? w1 : w2;
  int y = p >> 6, x2 = p & 63;
  float r[16];
  #pragma unroll
  for (int ic=0; ic<16; ++ic){
    const float* base = xr + (size_t)(bb*NCR + ic)*NL + (size_t)(2*y)*NWp + 2*x2;
    float a = base[0], b_ = base[1], c_ = base[NWp], d = base[NWp+1];
    r[ic] = mode ? 0.25f*(a+b_+c_+d) : fmaxf(fmaxf(a,b_), fmaxf(c_,d));
  }
  float* oo = out + ((size_t)(combo*NB + bb)*NCR)*NL2 + p;
  #pragma unroll
  for (int oc=0; oc<16; ++oc){
    float s = 0.f;
    #pragma unroll
    for (int ic=0; ic<16; ++ic) s += r[ic]*w[oc*16+ic];
    oo[(size_t)oc*NL2] = s;
  }
}

__global__ void k_dw_all(const float* __restrict__ in,
                         const float* __restrict__ w3, const float* __restrict__ b3,
                         const float* __restrict__ w5, const float* __restrict__ b5,
                         const float* __restrict__ w7, const float* __restrict__ b7,
                         float* __restrict__ out){
  int gid = blockIdx.x*256 + threadIdx.x;
  if (gid >= 6*NB*NCR*NL2) return;
  int p = gid & (NL2-1); int t = gid >> 12; int c = t & 15; int r2 = t >> 4;
  int bb = r2 & 1; int combo = r2 >> 1;
  int br = combo >> 1;
  int K = (br==0) ? 3 : (br==1) ? 5 : 7; int P = K >> 1;
  const float* w = (br==0) ? w3 : (br==1) ? w5 : w7;
  const float* bias = (br==0) ? b3 : (br==1) ? b5 : b7;
  int y = p >> 6, x = p & 63;
  const float* xi = in + ((size_t)(combo*NB + bb)*NCR + c)*NL2;
  float s = bias[c];
  for (int dy=0; dy<K; ++dy){
    int iy = y + dy - P;
    if ((unsigned)iy < 64u){
      for (int dx=0; dx<K; ++dx){
        int ix = x + dx - P;
        if ((unsigned)ix < 64u) s += xi[iy*64 + ix] * w[(c*K + dy)*K + dx];
      }
    }
  }
  out[gid] = s;
}

__global__ void k_up_all(const float* __restrict__ in, float* __restrict__ feats){
  int gid = blockIdx.x*256 + threadIdx.x;
  if (gid >= 6*NB*NCR*NL) return;
  int p = gid & (NL-1); int t = gid >> 14; int c = t & 15; int r2 = t >> 4;
  int bb = r2 & 1; int combo = r2 >> 1;
  int y = p >> 7, x = p & 127;
  const float sc = 63.0f/127.0f;
  float fy = y*sc; int ly = (int)floorf(fy); int hy = min(ly+1, 63); fy -= (float)ly;
  float fx = x*sc; int lx = (int)floorf(fx); int hx = min(lx+1, 63); float gx = fx - (float)lx;
  const float* xi = in + ((size_t)(combo*NB + bb)*NCR + c)*NL2;
  float v0 = xi[ly*64+lx]*(1.f-fy) + xi[hy*64+lx]*fy;
  float v1 = xi[ly*64+hx]*(1.f-fy) + xi[hy*64+hx]*fy;
  int coff = 32 + combo*16 + c;
  feats[(size_t)bb*128*NL + (size_t)coff*NL + p] = v0*(1.f-gx) + v1*gx;
}

__global__ void k_camean(const float* __restrict__ x, float* __restrict__ cay){
  __shared__ float red[256];
  int bc = blockIdx.x; int tid = threadIdx.x;
  float s = 0.f;
  for (int i = tid; i < NL; i += 256) s += x[(size_t)bc*NL + i];
  red[tid] = s; __syncthreads();
  for (int st=128; st>0; st>>=1){ if (tid<st) red[tid]+=red[tid+st]; __syncthreads(); }
  if (tid==0) cay[bc] = red[0] / (float)NL;
}

__global__ void k_camlp(const float* __restrict__ cay,
                        const float* __restrict__ w1, const float* __restrict__ b1,
                        const float* __restrict__ w2, const float* __restrict__ b2,
                        float* __restrict__ cas){
  __shared__ float z[NB*4];
  int tid = threadIdx.x;
  if (tid < NB*4){
    int bb = tid >> 2, j = tid & 3;
    float s = b1[j];
    for (int ic=0; ic<NC; ++ic) s += cay[bb*NC+ic]*w1[j*NC+ic];
    z[tid] = fmaxf(s, 0.f);
  }
  __syncthreads();
  if (tid < NB*NC){
    int bb = tid >> 6, oc = tid & 63;
    float s = b2[oc];
    #pragma unroll
    for (int j=0; j<4; ++j) s += z[bb*4+j]*w2[oc*4+j];
    cas[tid] = sigmoidf_(s);
  }
}

__global__ void k_wprod(const float* __restrict__ c11w, const float* __restrict__ c11b,
                        const float* __restrict__ rw, const float* __restrict__ rb,
                        float* __restrict__ crw, float* __restrict__ crb){
  int gid = blockIdx.x*256 + threadIdx.x;
  if (gid >= 4096) return;
  int o = gid >> 6, i = gid & 63;
  float s = 0.f;
  for (int k=0; k<64; ++k) s += c11w[o*64+k]*rw[k*64+i];
  crw[gid] = s;
  if (i == 0){
    float t = c11b[o];
    for (int k=0; k<64; ++k) t += c11w[o*64+k]*rb[k];
    crb[o] = t;
  }
}

__global__ __launch_bounds__(256,4) void k_attnmul(const float* __restrict__ x,
                          const float* __restrict__ feats,
                          const float* __restrict__ fw, const float* __restrict__ fb,
                          const float* __restrict__ cas, float* __restrict__ pre1){
  int gid = blockIdx.x*256 + threadIdx.x;
  int oc0 = blockIdx.y*16;
  int bb = gid >> 14, p = gid & (NL-1);
  const float* fi = feats + (size_t)bb*128*NL + p;
  float acc[16];
  #pragma unroll
  for (int j=0; j<16; ++j) acc[j] = fb[oc0+j];
  for (int k0=0; k0<128; k0+=8){
    float fr[8];
    #pragma unroll
    for (int j=0; j<8; ++j) fr[j] = fi[(size_t)(k0+j)*NL];
    #pragma unroll
    for (int j=0; j<16; ++j){
      #pragma unroll
      for (int t=0; t<8; ++t) acc[j] += fr[t]*fw[(oc0+j)*128+k0+t];
    }
  }
  const float* xb = x + (size_t)bb*NC*NL + p;
  float* po = pre1 + (size_t)bb*NC*NL + p;
  #pragma unroll
  for (int j=0; j<16; ++j){
    int oc = oc0 + j;
    float xv = xb[(size_t)oc*NL];
    po[(size_t)oc*NL] = xv*(sigmoidf_(acc[j]) + cas[bb*64+oc]);
  }
}

__global__ __launch_bounds__(256,4) void k_mask(const float* __restrict__ pre1,
                       const float* __restrict__ c11w,
                       const float* __restrict__ crw, const float* __restrict__ crb,
                       const float* __restrict__ x, float* __restrict__ mask){
  int gid = blockIdx.x*256 + threadIdx.x;
  int oc0 = blockIdx.y*16;
  int bb = gid >> 14, p = gid & (NL-1);
  const float* pi = pre1 + (size_t)bb*NC*NL + p;
  const float* xi = x + (size_t)bb*NC*NL + p;
  float acc[16];
  #pragma unroll
  for (int j=0; j<16; ++j) acc[j] = crb[oc0+j];
  for (int ic0=0; ic0<64; ic0+=8){
    float pr[8], xr8[8];
    #pragma unroll
    for (int j=0; j<8; ++j){ pr[j] = pi[(size_t)(ic0+j)*NL]; xr8[j] = xi[(size_t)(ic0+j)*NL]; }
    #pragma unroll
    for (int j=0; j<16; ++j){
      #pragma unroll
      for (int t=0; t<8; ++t)
        acc[j] += pr[t]*c11w[(oc0+j)*64+ic0+t] + xr8[t]*crw[(oc0+j)*64+ic0+t];
    }
  }
  float* mo = mask + (size_t)bb*NC*NL + p;
  #pragma unroll
  for (int j=0; j<16; ++j){
    int oc = oc0 + j;
    mo[(size_t)oc*NL] = acc[j] + xi[(size_t)oc*NL];
  }
}

// ---------------- phase 2 ----------------

__global__ __launch_bounds__(256,4) void k_xe(const float* __restrict__ mask,
                     const float* __restrict__ w, const float* __restrict__ b,
                     const float* __restrict__ rot,
                     _Float16* __restrict__ xeh, _Float16* __restrict__ xenh,
                     int* __restrict__ codes, int* __restrict__ hist){
  int gid = blockIdx.x*256 + threadIdx.x;
  int pix = gid >> 1, hf = gid & 1;
  int bb = pix >> 14, l = pix & (NL-1);
  const float* mi = mask + (size_t)bb*NC*NL + (size_t)hf*32*NL + l;
  float acc[16];
  #pragma unroll
  for (int oc=0; oc<16; ++oc) acc[oc] = hf ? 0.f : b[oc];
  for (int ic0=0; ic0<32; ic0+=16){
    float r[16];
    #pragma unroll
    for (int j=0; j<16; ++j) r[j] = mi[(size_t)(ic0+j)*NL];
    #pragma unroll
    for (int oc=0; oc<16; ++oc){
      #pragma unroll
      for (int j=0; j<16; ++j) acc[oc] += r[j]*w[oc*64 + hf*32 + ic0 + j];
    }
  }
  #pragma unroll
  for (int oc=0; oc<16; ++oc) acc[oc] += __shfl_xor(acc[oc], 1, 64);
  if (!hf){
    float n2 = 0.f;
    #pragma unroll
    for (int oc=0; oc<16; ++oc) n2 += acc[oc]*acc[oc];
    float inv = 1.0f / fmaxf(sqrtf(n2), 5e-5f);
    _Float16* ho = xeh + (size_t)pix*NCR;
    _Float16* no = xenh + (size_t)pix*NCR;
    #pragma unroll
    for (int g=0; g<4; ++g){
      half4 hv, nv;
      #pragma unroll
      for (int j=0; j<4; ++j){ hv[j] = (_Float16)acc[g*4+j]; nv[j] = (_Float16)(acc[g*4+j]*inv); }
      *(half4*)(ho + g*4) = hv;
      *(half4*)(no + g*4) = nv;
    }
  }
  #pragma unroll
  for (int hh=0; hh<2; ++hh){
    int h = hf*2 + hh;
    float rv[16];
    #pragma unroll
    for (int i=0; i<16; ++i){
      float s = 0.f;
      #pragma unroll
      for (int f=0; f<16; ++f) s += acc[f]*rot[(f*NHASH + h)*16 + i];
      rv[i] = s;
    }
    float best = -1e30f; int bi = 0;
    #pragma unroll
    for (int i=0; i<16; ++i){ if (rv[i] > best){ best = rv[i]; bi = i; } }
    #pragma unroll
    for (int i=0; i<16; ++i){ float val = -rv[i]; if (val > best){ best = val; bi = 16+i; } }
    int code = bi + h*32;
    codes[((bb*NHASH + h) << 14) + l] = code;
    int tile = h*64 + (l >> 8);
    atomicAdd(&hist[bb*NKEY*NTILE + code*NTILE + tile], 1);
  }
}

__global__ __launch_bounds__(256,4) void k_yeh(const float* __restrict__ mask,
                      const float* __restrict__ w, const float* __restrict__ b,
                      const int* __restrict__ undo, _Float16* __restrict__ vs){
  int gid = blockIdx.x*256 + threadIdx.x;
  int oc0 = blockIdx.y*16;
  int bb = gid >> 14, l = gid & (NL-1);
  const float* mi = mask + (size_t)bb*NC*NL + l;
  float acc[16];
  #pragma unroll
  for (int j=0; j<16; ++j) acc[j] = b[oc0+j];
  for (int ic0=0; ic0<64; ic0+=8){
    float r[8];
    #pragma unroll
    for (int j=0; j<8; ++j) r[j] = mi[(size_t)(ic0+j)*NL];
    #pragma unroll
    for (int j=0; j<16; ++j){
      #pragma unroll
      for (int t=0; t<8; ++t) acc[j] += r[t]*w[(oc0+j)*64+ic0+t];
    }
  }
  half8 h0, h1;
  #pragma unroll
  for (int j=0; j<8; ++j){ h0[j] = (_Float16)acc[j]; h1[j] = (_Float16)acc[8+j]; }
  const int* ub = undo + bb*TOT;
  #pragma unroll
  for (int h=0; h<4; ++h){
    int pos = ub[h*NL + l];
    _Float16* vo = vs + ((size_t)bb*TOT + pos)*64 + oc0;
    *(half8*)(vo) = h0;
    *(half8*)(vo + 8) = h1;
  }
}

__global__ void k_scan(const int* __restrict__ hist, int* __restrict__ offs){
  __shared__ int part[256];
  int bb = blockIdx.x; int t = threadIdx.x;
  const int* hi = hist + (size_t)bb*NKEY*NTILE;
  int* oo = offs + (size_t)bb*NKEY*NTILE;
  int s = 0;
  for (int i=0; i<128; ++i) s += hi[t*128 + i];
  part[t] = s; __syncthreads();
  int v = s;
  for (int off=1; off<256; off<<=1){
    int u = (t >= off) ? part[t-off] : 0;
    __syncthreads();
    v += u; part[t] = v;
    __syncthreads();
  }
  int run = v - s;
  for (int i=0; i<128; ++i){ int q = hi[t*128+i]; oo[t*128+i] = run; run += q; }
}

__global__ __launch_bounds__(256) void k_scatter(const int* __restrict__ codes,
                          const int* __restrict__ offs,
                          const _Float16* __restrict__ xeh, const _Float16* __restrict__ xenh,
                          int* __restrict__ undo,
                          _Float16* __restrict__ qs, _Float16* __restrict__ ks){
  __shared__ int cnt[4][NKEY];
  int wid = threadIdx.x >> 6, lane = threadIdx.x & 63;
  int t4 = blockIdx.x;
  int bb = t4 >> 6;
  int tile = (t4 & 63)*4 + wid;
  cnt[wid][lane] = 0; cnt[wid][64+lane] = 0;
  const int* cb = codes + bb*TOT;
  const int* ob = offs + (size_t)bb*NKEY*NTILE;
  int* ub = undo + bb*TOT;
  for (int g=0; g<4; ++g){
    int j = tile*TILESZ + g*64 + lane;
    int k = cb[j];
    unsigned long long m = ~0ull;
    #pragma unroll
    for (int bit=0; bit<7; ++bit){
      unsigned long long bmask = __ballot((k >> bit) & 1);
      m &= ((k >> bit) & 1) ? bmask : ~bmask;
    }
    int rank = __popcll(m & ((1ull << lane) - 1ull));
    int leader = __ffsll((unsigned long long)m) - 1;
    int base = 0;
    if (lane == leader){
      base = cnt[wid][k];
      cnt[wid][k] = base + __popcll(m);
    }
    base = __shfl(base, leader, 64);
    int pos = ob[k*NTILE + tile] + base + rank;
    ub[j] = pos;
    int l = j & (NL-1);
    const _Float16* qp = xeh + ((size_t)bb*NL + l)*16;
    const _Float16* kp = xenh + ((size_t)bb*NL + l)*16;
    _Float16* qo = qs + ((size_t)bb*TOT + pos)*16;
    _Float16* ko = ks + ((size_t)bb*TOT + pos)*16;
    *(half8*)(qo)     = *(const half8*)(qp);
    *(half8*)(qo + 8) = *(const half8*)(qp + 8);
    *(half8*)(ko)     = *(const half8*)(kp);
    *(half8*)(ko + 8) = *(const half8*)(kp + 8);
    __threadfence_block();
  }
}

// MFMA flash attention: 128-key staging tiles (12 iters, half the barriers),
// sorted operands, T14 prefetch, native-exp2 softmax, permuted V^T (b128 PV reads).
__global__ __launch_bounds__(512) void k_attn(
    const _Float16* __restrict__ qs, const _Float16* __restrict__ ks,
    const _Float16* __restrict__ vs,
    _Float16* __restrict__ retb, float* __restrict__ bsc){
  __shared__ _Float16 kt[128*20];
  __shared__ _Float16 vt[64*136];   // [c][128 permuted keys + pad], stride 136
  int blk = blockIdx.x;
  int qh = blk & 1; int kk = (blk >> 1) & 31; int h = (blk >> 6) & 3; int bb = blk >> 8;
  int tid = threadIdx.x;
  int w = tid >> 6, lane = tid & 63, col = lane & 15, grp = lane >> 4;
  int qbase = h*NL + kk*CHUNKSZ + qh*256 + w*32;

  half4 qfr[2]; int posq[2];
  #pragma unroll
  for (int qf=0; qf<2; ++qf){
    posq[qf] = qbase + qf*16 + col;
    qfr[qf] = *(const half4*)(qs + ((size_t)bb*TOT + posq[qf])*16 + grp*4);
    #pragma unroll
    for (int i=0; i<4; ++i) qfr[qf][i] = (_Float16)((float)qfr[qf][i] * 1.44269504f);
  }

  f32x4 O[4][2];
  #pragma unroll
  for (int a=0; a<4; ++a)
    #pragma unroll
    for (int b=0; b<2; ++b) O[a][b] = (f32x4){0.f,0.f,0.f,0.f};
  float m_[2] = {-1e30f,-1e30f};
  float ssum[2] = {0.f,0.f};

  // V-stage mapping: 128 keys x 16 channels per thread-group
  int kx = tid & 127, c0 = (tid >> 7) * 16;
  int kxl = kx & 31;
  int vcol = (kx & 96) + (((kxl & 12) << 1) + ((kxl & 16) >> 2) + (kxl & 3));
  // K-stage mapping: threads 0..255 -> 128 rows x 2 half8
  int kr = tid >> 1, khf = tid & 1;

  #define SPOS(jj) ({ int sec_ = (jj) >> 9; int j0_ = (jj) & 511; \
      int cc_ = kk + ((sec_==1) ? -1 : (sec_==2) ? 1 : 0); \
      cc_ = (cc_ + NCHUNKS) & (NCHUNKS-1); h*NL + cc_*CHUNKSZ + j0_; })

  // prologue: load tile 0 (128 keys)
  half8 vv0 = *(const half8*)(vs + ((size_t)bb*TOT + SPOS(kx))*64 + c0);
  half8 vv1 = *(const half8*)(vs + ((size_t)bb*TOT + SPOS(kx))*64 + c0 + 8);
  half8 kv;
  if (tid < 256) kv = *(const half8*)(ks + ((size_t)bb*TOT + SPOS(kr))*16 + khf*8);

  for (int t=0; t<12; ++t){
    __syncthreads();
    #pragma unroll
    for (int j=0; j<8; ++j) vt[(c0+j)*136 + vcol] = vv0[j];
    #pragma unroll
    for (int j=0; j<8; ++j) vt[(c0+8+j)*136 + vcol] = vv1[j];
    if (tid < 256) *(half8*)(kt + kr*20 + khf*8) = kv;
    __syncthreads();
    if (t+1 < 12){
      int jj = (t+1)*128;
      vv0 = *(const half8*)(vs + ((size_t)bb*TOT + SPOS(jj + kx))*64 + c0);
      vv1 = *(const half8*)(vs + ((size_t)bb*TOT + SPOS(jj + kx))*64 + c0 + 8);
      if (tid < 256) kv = *(const half8*)(ks + ((size_t)bb*TOT + SPOS(jj + kr))*16 + khf*8);
    }

    // two 64-key compute sub-passes
    #pragma unroll
    for (int hh=0; hh<2; ++hh){
      int kb0 = hh*64;
      f32x4 S[4][2];
      #pragma unroll
      for (int kb=0; kb<4; ++kb){
        half4 ka = *(const half4*)(kt + (kb0 + kb*16 + col)*20 + grp*4);
        #pragma unroll
        for (int qf=0; qf<2; ++qf)
          S[kb][qf] = __builtin_amdgcn_mfma_f32_16x16x16f16(
              ka, qfr[qf], (f32x4){0.f,0.f,0.f,0.f}, 0, 0, 0);
      }

      half8 pb[2][2];
      #pragma unroll
      for (int qf=0; qf<2; ++qf){
        float mtl = -1e30f;
        #pragma unroll
        for (int kb=0; kb<4; ++kb)
          #pragma unroll
          for (int i=0; i<4; ++i) mtl = fmaxf(mtl, S[kb][qf][i]);
        if (__any(mtl > m_[qf] + 11.5f)){
          float mt = fmaxf(mtl, __shfl_xor(mtl, 16, 64));
          mt = fmaxf(mt, __shfl_xor(mt, 32, 64));
          float mn = fmaxf(m_[qf], mt);
          float sc = EXP2F(m_[qf] - mn);
          ssum[qf] *= sc;
          m_[qf] = mn;
          #pragma unroll
          for (int cf=0; cf<4; ++cf)
            #pragma unroll
            for (int i=0; i<4; ++i) O[cf][qf][i] *= sc;
        }
        float ps = 0.f;
        #pragma unroll
        for (int k2=0; k2<2; ++k2){
          half8 hb;
          #pragma unroll
          for (int i=0; i<4; ++i){
            float p0 = EXP2F(S[2*k2][qf][i]   - m_[qf]);
            float p1 = EXP2F(S[2*k2+1][qf][i] - m_[qf]);
            ps += p0 + p1;
            hb[i]   = (_Float16)p0;
            hb[4+i] = (_Float16)p1;
          }
          pb[qf][k2] = hb;
        }
        ssum[qf] += ps;
      }

      #pragma unroll
      for (int cf=0; cf<4; ++cf){
        #pragma unroll
        for (int k2=0; k2<2; ++k2){
          half8 va = *(const half8*)(vt + (cf*16 + col)*136 + kb0 + k2*32 + grp*8);
          #pragma unroll
          for (int qf=0; qf<2; ++qf)
            O[cf][qf] = __builtin_amdgcn_mfma_f32_16x16x32_f16(
                va, pb[qf][k2], O[cf][qf], 0, 0, 0);
        }
      }
    }
  }
  #undef SPOS

  #pragma unroll
  for (int qf=0; qf<2; ++qf){
    float st = ssum[qf];
    st += __shfl_xor(st, 16, 64);
    st += __shfl_xor(st, 32, 64);
    float inv = 1.0f/st;
    size_t rb = ((size_t)bb*TOT + posq[qf])*64;
    #pragma unroll
    for (int cf=0; cf<4; ++cf){
      half4 o;
      #pragma unroll
      for (int i=0; i<4; ++i) o[i] = (_Float16)(O[cf][qf][i]*inv);
      *(half4*)(retb + rb + cf*16 + grp*4) = o;
    }
    if (grp == 0) bsc[(size_t)bb*TOT + posq[qf]] = m_[qf]*0.69314718f + logf(st);
  }
}

__global__ __launch_bounds__(256,4) void k_combine(const _Float16* __restrict__ retb,
                          const float* __restrict__ bsc,
                          const int* __restrict__ undo, const float* __restrict__ mask,
                          float* __restrict__ fea){
  int gid = blockIdx.x*256 + threadIdx.x;
  int c0 = blockIdx.y*32;
  int bb = gid >> 14; int l = gid & (NL-1);
  const int* ub = undo + bb*TOT;
  int pos[4]; float sc[4];
  #pragma unroll
  for (int h=0; h<4; ++h){ pos[h] = ub[h*NL + l]; sc[h] = bsc[bb*TOT + pos[h]]; }
  float mx = fmaxf(fmaxf(sc[0],sc[1]), fmaxf(sc[2],sc[3]));
  float e[4]; float tot = 0.f;
  #pragma unroll
  for (int h=0; h<4; ++h){ e[h] = __expf(sc[h]-mx); tot += e[h]; }
  float inv = 0.1f/tot;
  const float* mb_ = mask + (size_t)bb*NC*NL + l;
  float* fo = fea + (size_t)bb*NC*NL + l;
  const _Float16* r0 = retb + ((size_t)bb*TOT + pos[0])*NC + c0;
  const _Float16* r1 = retb + ((size_t)bb*TOT + pos[1])*NC + c0;
  const _Float16* r2 = retb + ((size_t)bb*TOT + pos[2])*NC + c0;
  const _Float16* r3 = retb + ((size_t)bb*TOT + pos[3])*NC + c0;
  #pragma unroll
  for (int g=0; g<4; ++g){
    half8 v0 = *(const half8*)(r0 + g*8);
    half8 v1 = *(const half8*)(r1 + g*8);
    half8 v2 = *(const half8*)(r2 + g*8);
    half8 v3 = *(const half8*)(r3 + g*8);
    #pragma unroll
    for (int j=0; j<8; ++j){
      int c = c0 + g*8 + j;
      float v = (float)v0[j]*e[0] + (float)v1[j]*e[1] + (float)v2[j]*e[2] + (float)v3[j]*e[3];
      fo[(size_t)c*NL] = v*inv + mb_[(size_t)c*NL];
    }
  }
}

__global__ __launch_bounds__(256,4) void k_collect(const float* __restrict__ fea,
                          const float* __restrict__ w,
                          const float* __restrict__ b, const float* __restrict__ x,
                          float* __restrict__ out){
  int gid = blockIdx.x*256 + threadIdx.x;
  int oc0 = blockIdx.y*16;
  int bb = gid >> 14, p = gid & (NL-1);
  const float* fi = fea + (size_t)bb*NC*NL + p;
  const float* xi = x + (size_t)bb*NC*NL + p;
  float acc[16];
  #pragma unroll
  for (int j=0; j<16; ++j) acc[j] = b[oc0+j];
  for (int ic0=0; ic0<64; ic0+=8){
    float r[8];
    #pragma unroll
    for (int j=0; j<8; ++j) r[j] = fi[(size_t)(ic0+j)*NL];
    #pragma unroll
    for (int j=0; j<16; ++j){
      #pragma unroll
      for (int t=0; t<8; ++t) acc[j] += r[t]*w[(oc0+j)*64+ic0+t];
    }
  }
  float* oo = out + (size_t)bb*NC*NL + p;
  #pragma unroll
  for (int j=0; j<16; ++j){
    int oc = oc0 + j;
    oo[(size_t)oc*NL] = acc[j] + xi[(size_t)oc*NL];
  }
}

// ---------------- launcher ----------------
extern "C" void kernel_launch(void* const* d_in, const int* in_sizes, int n_in,
                              void* d_out, int out_size, void* d_ws, size_t ws_size,
                              hipStream_t stream) {
  const float* x        = (const float*)d_in[0];
  const float* spa_dw   = (const float*)d_in[1];
  const float* spa_db   = (const float*)d_in[2];
  const float* s0_pw    = (const float*)d_in[3];
  const float* s0_dww   = (const float*)d_in[4];
  const float* s0_dwb   = (const float*)d_in[5];
  const float* fus_w    = (const float*)d_in[15];
  const float* fus_b    = (const float*)d_in[16];
  const float* res_w    = (const float*)d_in[17];
  const float* res_b    = (const float*)d_in[18];
  const float* ca_w1    = (const float*)d_in[19];
  const float* ca_b1    = (const float*)d_in[20];
  const float* ca_w2    = (const float*)d_in[21];
  const float* ca_b2    = (const float*)d_in[22];
  const float* c11_w    = (const float*)d_in[23];
  const float* c11_b    = (const float*)d_in[24];
  const float* match_w  = (const float*)d_in[25];
  const float* match_b  = (const float*)d_in[26];
  const float* asm_w    = (const float*)d_in[27];
  const float* asm_b    = (const float*)d_in[28];
  const float* rot      = (const float*)d_in[29];
  const float* col_w    = (const float*)d_in[30];
  const float* col_b    = (const float*)d_in[31];
  float* out = (float*)d_out;

  float* ws    = (float*)d_ws;
  float* mask  = ws + OFF_MASK;
  float* fea   = ws + OFF_FEA;
  _Float16* xeh  = (_Float16*)(ws + OFF_XEH);
  _Float16* xenh = (_Float16*)(ws + OFF_XENH);
  _Float16* vsort = (_Float16*)(ws + OFF_VS);
  _Float16* qsort = (_Float16*)(ws + OFF_QS);
  _Float16* ksort = (_Float16*)(ws + OFF_KS);
  _Float16* retb = (_Float16*)(ws + OFF_RET);
  float* bsc   = ws + OFF_BSC;
  int*   ib    = (int*)(ws + OFF_INT);
  int* codes   = ib + IOFF_CODES;
  int* undo    = ib + IOFF_UNDO;
  int* hist    = ib + IOFF_HIST;
  int* offs    = ib + IOFF_OFFS;
  float* cay   = ws + OFF_CAY;
  float* cas   = ws + OFF_CAS;
  float* crw   = ws + OFF_CRW;
  float* crb   = ws + OFF_CRB;
  float* xr    = ws + OFF_XR;
  float* feats = ws + OFF_FEATS;
  float* ptmp  = ws + OFF_PTMP;
  float* dwt   = ws + OFF_DWT;
  float* pre1  = ws + OFF_PRE1;

  // ---- phase 1 ----
  k_xr<<<(NB*NL*2)/256, 256, 0, stream>>>(x, spa_dw, spa_db, xr);
  k_wprod<<<16, 256, 0, stream>>>(c11_w, c11_b, res_w, res_b, crw, crb);
  k_s0<<<dim3((NB*NL)/256, 2), 256, 0, stream>>>(xr, s0_pw, s0_dww, s0_dwb, feats);
  k_pw16_all<<<(6*NB*NL2)/256, 256, 0, stream>>>(xr,
      (const float*)d_in[6], (const float*)d_in[9], (const float*)d_in[12], ptmp);
  k_dw_all<<<(6*NB*NCR*NL2)/256, 256, 0, stream>>>(ptmp,
      (const float*)d_in[7], (const float*)d_in[8],
      (const float*)d_in[10], (const float*)d_in[11],
      (const float*)d_in[13], (const float*)d_in[14], dwt);
  k_up_all<<<(6*NB*NCR*NL)/256, 256, 0, stream>>>(dwt, feats);
  k_camean<<<NB*NC, 256, 0, stream>>>(x, cay);
  k_camlp<<<1, 128, 0, stream>>>(cay, ca_w1, ca_b1, ca_w2, ca_b2, cas);
  k_attnmul<<<dim3((NB*NL)/256, 4), 256, 0, stream>>>(x, feats, fus_w, fus_b, cas, pre1);
  k_mask<<<dim3((NB*NL)/256, 4), 256, 0, stream>>>(pre1, c11_w, crw, crb, x, mask);

  // ---- phase 2 ----
  (void)hipMemsetAsync(hist, 0, (size_t)NB*NKEY*NTILE*sizeof(int), stream);
  k_xe<<<(NB*NL*2)/256, 256, 0, stream>>>(mask, match_w, match_b, rot, xeh, xenh, codes, hist);
  k_scan<<<NB, 256, 0, stream>>>(hist, offs);
  k_scatter<<<NB*NTILE/4, 256, 0, stream>>>(codes, offs, xeh, xenh, undo, qsort, ksort);
  k_yeh<<<dim3((NB*NL)/256, 4), 256, 0, stream>>>(mask, asm_w, asm_b, undo, vsort);
  k_attn<<<NB*NHASH*NCHUNKS*2, 512, 0, stream>>>(qsort, ksort, vsort, retb, bsc);
  k_combine<<<dim3((NB*NL)/256, 2), 256, 0, stream>>>(retb, bsc, undo, mask, fea);
  k_collect<<<dim3((NB*NL)/256, 4), 256, 0, stream>>>(fea, col_w, col_b, x, out);
}

// Round 17
// 315.165 us; speedup vs baseline: 1.0820x; 1.0050x over previous
//
#include <hip/hip_runtime.h>
#include <math.h>

// ---------------- problem constants ----------------
static constexpr int NB = 2;
static constexpr int NC = 64;
static constexpr int NHp = 128, NWp = 128;
static constexpr int NL = NHp * NWp;     // 16384
static constexpr int NCR = 16;
static constexpr int NL2 = 64 * 64;      // 4096
static constexpr int NHASH = 4;
static constexpr int CHUNKSZ = 512;
static constexpr int NCHUNKS = 32;
static constexpr int TOT = NHASH * NL;   // 65536
static constexpr int NKEY = 128;
static constexpr int NTILE = 256;
static constexpr int TILESZ = TOT / NTILE; // 256

typedef _Float16 half4 __attribute__((ext_vector_type(4)));
typedef _Float16 half8 __attribute__((ext_vector_type(8)));
typedef float f32x4 __attribute__((ext_vector_type(4)));

#if __has_builtin(__builtin_amdgcn_exp2f)
  #define EXP2F(x) __builtin_amdgcn_exp2f(x)
#else
  #define EXP2F(x) __expf(0.69314718f*(x))
#endif

// ---------------- workspace layout (float units) ----------------
static constexpr size_t OFF_MASK = 0;
static constexpr size_t OFF_FEA  = OFF_MASK + (size_t)NB*NC*NL;
static constexpr size_t OFF_XE   = OFF_FEA  + (size_t)NB*NC*NL;
static constexpr size_t OFF_XEH  = OFF_XE   + (size_t)NB*NL*NCR;
static constexpr size_t OFF_XENH = OFF_XEH  + (size_t)NB*NL*NCR/2;
static constexpr size_t OFF_VS   = OFF_XENH + (size_t)NB*NL*NCR/2;
static constexpr size_t OFF_RET  = OFF_VS   + (size_t)NB*TOT*NC/2;
static constexpr size_t OFF_BSC  = OFF_RET  + (size_t)NB*TOT*NC/2;
static constexpr size_t OFF_INT  = OFF_BSC  + (size_t)NB*TOT;
static constexpr size_t IOFF_CODES = 0;
static constexpr size_t IOFF_IDX   = IOFF_CODES + (size_t)NB*TOT;
static constexpr size_t IOFF_UNDO  = IOFF_IDX   + (size_t)NB*TOT;
static constexpr size_t IOFF_HIST  = IOFF_UNDO  + (size_t)NB*TOT;
static constexpr size_t IOFF_OFFS  = IOFF_HIST  + (size_t)NB*NKEY*NTILE/2;
static constexpr size_t IOFF_END   = IOFF_OFFS  + (size_t)NB*NKEY*NTILE/2;
static constexpr size_t OFF_CAY = OFF_INT + IOFF_END;
static constexpr size_t OFF_CAS = OFF_CAY + 128;
static constexpr size_t OFF_CRW = OFF_CAS + 128;
static constexpr size_t OFF_CRB = OFF_CRW + 4096;
static constexpr size_t OFF_QS = OFF_FEA;
static constexpr size_t OFF_KS = OFF_QS + (size_t)NB*TOT*NCR/2;
static_assert(OFF_KS + (size_t)NB*TOT*NCR/2 <= OFF_XE, "qs/ks fit in fea region");
static constexpr size_t OFF_PTMP  = OFF_FEA;
static constexpr size_t OFF_DWT   = OFF_PTMP + (size_t)6*NB*NCR*NL2;
static_assert(OFF_DWT + (size_t)6*NB*NCR*NL2 <= OFF_XE, "halfres overlay fits");
static constexpr size_t OFF_XR    = OFF_XE;
static constexpr size_t OFF_FEATS = OFF_XR + (size_t)NB*NCR*NL;
static_assert(OFF_FEATS + (size_t)NB*128*NL <= OFF_RET, "feats overlay fits");
static constexpr size_t OFF_PRE1  = OFF_FEA;

__device__ __forceinline__ float sigmoidf_(float v){ return 1.0f/(1.0f + expf(-v)); }

// ---------------- phase 1 ----------------

__global__ __launch_bounds__(256,4) void k_xr(const float* __restrict__ x,
                     const float* __restrict__ w,
                     const float* __restrict__ b, float* __restrict__ xr){
  int gid = blockIdx.x*256 + threadIdx.x;
  int pix = gid >> 1, hf = gid & 1;
  int bb = pix >> 14, p = pix & (NL-1);
  const float* xi = x + (size_t)bb*NC*NL + (size_t)hf*32*NL + p;
  float acc[16];
  #pragma unroll
  for (int oc=0; oc<16; ++oc) acc[oc] = hf ? 0.f : b[oc];
  for (int ic0=0; ic0<32; ic0+=16){
    float r[16];
    #pragma unroll
    for (int j=0; j<16; ++j) r[j] = xi[(size_t)(ic0+j)*NL];
    #pragma unroll
    for (int oc=0; oc<16; ++oc){
      #pragma unroll
      for (int j=0; j<16; ++j) acc[oc] += r[j]*w[oc*64 + hf*32 + ic0 + j];
    }
  }
  #pragma unroll
  for (int oc=0; oc<16; ++oc) acc[oc] += __shfl_xor(acc[oc], 1, 64);
  if (!hf){
    float* xo = xr + (size_t)bb*NCR*NL + p;
    #pragma unroll
    for (int oc=0; oc<16; ++oc) xo[(size_t)oc*NL] = acc[oc];
  }
}

__global__ __launch_bounds__(256,4) void k_s0(const float* __restrict__ xr,
                     const float* __restrict__ pw,
                     const float* __restrict__ dww, const float* __restrict__ dwb,
                     float* __restrict__ feats){
  int gid = blockIdx.x*256 + threadIdx.x;
  int oc0 = blockIdx.y*16;
  int bb = gid >> 14, p = gid & (NL-1);
  const float* xi = xr + (size_t)bb*NCR*NL + p;
  float r[16];
  #pragma unroll
  for (int ic=0; ic<16; ++ic) r[ic] = xi[(size_t)ic*NL];
  float* fo = feats + (size_t)bb*128*NL + p;
  #pragma unroll
  for (int j=0; j<16; ++j){
    int oc = oc0 + j;
    float s = 0.f;
    #pragma unroll
    for (int ic=0; ic<16; ++ic) s += r[ic]*pw[oc*16+ic];
    fo[(size_t)oc*NL] = s*dww[oc] + dwb[oc];
  }
}

__global__ void k_pw16_all(const float* __restrict__ xr,
                           const float* __restrict__ w0, const float* __restrict__ w1,
                           const float* __restrict__ w2, float* __restrict__ out){
  int gid = blockIdx.x*256 + threadIdx.x;
  if (gid >= 6*NB*NL2) return;
  int p = gid & (NL2-1); int t = gid >> 12; int bb = t & 1; int combo = t >> 1;
  int br = combo >> 1, mode = combo & 1;
  const float* w = (br==0) ? w0 : (br==1) ? w1 : w2;
  int y = p >> 6, x2 = p & 63;
  float r[16];
  #pragma unroll
  for (int ic=0; ic<16; ++ic){
    const float* base = xr + (size_t)(bb*NCR + ic)*NL + (size_t)(2*y)*NWp + 2*x2;
    float a = base[0], b_ = base[1], c_ = base[NWp], d = base[NWp+1];
    r[ic] = mode ? 0.25f*(a+b_+c_+d) : fmaxf(fmaxf(a,b_), fmaxf(c_,d));
  }
  float* oo = out + ((size_t)(combo*NB + bb)*NCR)*NL2 + p;
  #pragma unroll
  for (int oc=0; oc<16; ++oc){
    float s = 0.f;
    #pragma unroll
    for (int ic=0; ic<16; ++ic) s += r[ic]*w[oc*16+ic];
    oo[(size_t)oc*NL2] = s;
  }
}

__global__ void k_dw_all(const float* __restrict__ in,
                         const float* __restrict__ w3, const float* __restrict__ b3,
                         const float* __restrict__ w5, const float* __restrict__ b5,
                         const float* __restrict__ w7, const float* __restrict__ b7,
                         float* __restrict__ out){
  int gid = blockIdx.x*256 + threadIdx.x;
  if (gid >= 6*NB*NCR*NL2) return;
  int p = gid & (NL2-1); int t = gid >> 12; int c = t & 15; int r2 = t >> 4;
  int bb = r2 & 1; int combo = r2 >> 1;
  int br = combo >> 1;
  int K = (br==0) ? 3 : (br==1) ? 5 : 7; int P = K >> 1;
  const float* w = (br==0) ? w3 : (br==1) ? w5 : w7;
  const float* bias = (br==0) ? b3 : (br==1) ? b5 : b7;
  int y = p >> 6, x = p & 63;
  const float* xi = in + ((size_t)(combo*NB + bb)*NCR + c)*NL2;
  float s = bias[c];
  for (int dy=0; dy<K; ++dy){
    int iy = y + dy - P;
    if ((unsigned)iy < 64u){
      for (int dx=0; dx<K; ++dx){
        int ix = x + dx - P;
        if ((unsigned)ix < 64u) s += xi[iy*64 + ix] * w[(c*K + dy)*K + dx];
      }
    }
  }
  out[gid] = s;
}

__global__ void k_up_all(const float* __restrict__ in, float* __restrict__ feats){
  int gid = blockIdx.x*256 + threadIdx.x;
  if (gid >= 6*NB*NCR*NL) return;
  int p = gid & (NL-1); int t = gid >> 14; int c = t & 15; int r2 = t >> 4;
  int bb = r2 & 1; int combo = r2 >> 1;
  int y = p >> 7, x = p & 127;
  const float sc = 63.0f/127.0f;
  float fy = y*sc; int ly = (int)floorf(fy); int hy = min(ly+1, 63); fy -= (float)ly;
  float fx = x*sc; int lx = (int)floorf(fx); int hx = min(lx+1, 63); float gx = fx - (float)lx;
  const float* xi = in + ((size_t)(combo*NB + bb)*NCR + c)*NL2;
  float v0 = xi[ly*64+lx]*(1.f-fy) + xi[hy*64+lx]*fy;
  float v1 = xi[ly*64+hx]*(1.f-fy) + xi[hy*64+hx]*fy;
  int coff = 32 + combo*16 + c;
  feats[(size_t)bb*128*NL + (size_t)coff*NL + p] = v0*(1.f-gx) + v1*gx;
}

__global__ void k_camean(const float* __restrict__ x, float* __restrict__ cay){
  __shared__ float red[256];
  int bc = blockIdx.x; int tid = threadIdx.x;
  float s = 0.f;
  for (int i = tid; i < NL; i += 256) s += x[(size_t)bc*NL + i];
  red[tid] = s; __syncthreads();
  for (int st=128; st>0; st>>=1){ if (tid<st) red[tid]+=red[tid+st]; __syncthreads(); }
  if (tid==0) cay[bc] = red[0] / (float)NL;
}

__global__ void k_camlp(const float* __restrict__ cay,
                        const float* __restrict__ w1, const float* __restrict__ b1,
                        const float* __restrict__ w2, const float* __restrict__ b2,
                        float* __restrict__ cas){
  __shared__ float z[NB*4];
  int tid = threadIdx.x;
  if (tid < NB*4){
    int bb = tid >> 2, j = tid & 3;
    float s = b1[j];
    for (int ic=0; ic<NC; ++ic) s += cay[bb*NC+ic]*w1[j*NC+ic];
    z[tid] = fmaxf(s, 0.f);
  }
  __syncthreads();
  if (tid < NB*NC){
    int bb = tid >> 6, oc = tid & 63;
    float s = b2[oc];
    #pragma unroll
    for (int j=0; j<4; ++j) s += z[bb*4+j]*w2[oc*4+j];
    cas[tid] = sigmoidf_(s);
  }
}

__global__ void k_wprod(const float* __restrict__ c11w, const float* __restrict__ c11b,
                        const float* __restrict__ rw, const float* __restrict__ rb,
                        float* __restrict__ crw, float* __restrict__ crb){
  int gid = blockIdx.x*256 + threadIdx.x;
  if (gid >= 4096) return;
  int o = gid >> 6, i = gid & 63;
  float s = 0.f;
  for (int k=0; k<64; ++k) s += c11w[o*64+k]*rw[k*64+i];
  crw[gid] = s;
  if (i == 0){
    float t = c11b[o];
    for (int k=0; k<64; ++k) t += c11w[o*64+k]*rb[k];
    crb[o] = t;
  }
}

__global__ __launch_bounds__(256,4) void k_attnmul(const float* __restrict__ x,
                          const float* __restrict__ feats,
                          const float* __restrict__ fw, const float* __restrict__ fb,
                          const float* __restrict__ cas, float* __restrict__ pre1){
  int gid = blockIdx.x*256 + threadIdx.x;
  int oc0 = blockIdx.y*16;
  int bb = gid >> 14, p = gid & (NL-1);
  const float* fi = feats + (size_t)bb*128*NL + p;
  float acc[16];
  #pragma unroll
  for (int j=0; j<16; ++j) acc[j] = fb[oc0+j];
  for (int k0=0; k0<128; k0+=8){
    float fr[8];
    #pragma unroll
    for (int j=0; j<8; ++j) fr[j] = fi[(size_t)(k0+j)*NL];
    #pragma unroll
    for (int j=0; j<16; ++j){
      #pragma unroll
      for (int t=0; t<8; ++t) acc[j] += fr[t]*fw[(oc0+j)*128+k0+t];
    }
  }
  const float* xb = x + (size_t)bb*NC*NL + p;
  float* po = pre1 + (size_t)bb*NC*NL + p;
  #pragma unroll
  for (int j=0; j<16; ++j){
    int oc = oc0 + j;
    float xv = xb[(size_t)oc*NL];
    po[(size_t)oc*NL] = xv*(sigmoidf_(acc[j]) + cas[bb*64+oc]);
  }
}

__global__ __launch_bounds__(256,4) void k_mask(const float* __restrict__ pre1,
                       const float* __restrict__ c11w,
                       const float* __restrict__ crw, const float* __restrict__ crb,
                       const float* __restrict__ x, float* __restrict__ mask){
  int gid = blockIdx.x*256 + threadIdx.x;
  int oc0 = blockIdx.y*16;
  int bb = gid >> 14, p = gid & (NL-1);
  const float* pi = pre1 + (size_t)bb*NC*NL + p;
  const float* xi = x + (size_t)bb*NC*NL + p;
  float acc[16];
  #pragma unroll
  for (int j=0; j<16; ++j) acc[j] = crb[oc0+j];
  for (int ic0=0; ic0<64; ic0+=8){
    float pr[8], xr8[8];
    #pragma unroll
    for (int j=0; j<8; ++j){ pr[j] = pi[(size_t)(ic0+j)*NL]; xr8[j] = xi[(size_t)(ic0+j)*NL]; }
    #pragma unroll
    for (int j=0; j<16; ++j){
      #pragma unroll
      for (int t=0; t<8; ++t)
        acc[j] += pr[t]*c11w[(oc0+j)*64+ic0+t] + xr8[t]*crw[(oc0+j)*64+ic0+t];
    }
  }
  float* mo = mask + (size_t)bb*NC*NL + p;
  #pragma unroll
  for (int j=0; j<16; ++j){
    int oc = oc0 + j;
    mo[(size_t)oc*NL] = acc[j] + xi[(size_t)oc*NL];
  }
}

// ---------------- phase 2 ----------------

__global__ __launch_bounds__(256,4) void k_xe(const float* __restrict__ mask,
                     const float* __restrict__ w, const float* __restrict__ b,
                     const float* __restrict__ rot,
                     _Float16* __restrict__ xeh, _Float16* __restrict__ xenh,
                     int* __restrict__ codes, int* __restrict__ hist){
  int gid = blockIdx.x*256 + threadIdx.x;
  int pix = gid >> 1, hf = gid & 1;
  int bb = pix >> 14, l = pix & (NL-1);
  const float* mi = mask + (size_t)bb*NC*NL + (size_t)hf*32*NL + l;
  float acc[16];
  #pragma unroll
  for (int oc=0; oc<16; ++oc) acc[oc] = hf ? 0.f : b[oc];
  for (int ic0=0; ic0<32; ic0+=16){
    float r[16];
    #pragma unroll
    for (int j=0; j<16; ++j) r[j] = mi[(size_t)(ic0+j)*NL];
    #pragma unroll
    for (int oc=0; oc<16; ++oc){
      #pragma unroll
      for (int j=0; j<16; ++j) acc[oc] += r[j]*w[oc*64 + hf*32 + ic0 + j];
    }
  }
  #pragma unroll
  for (int oc=0; oc<16; ++oc) acc[oc] += __shfl_xor(acc[oc], 1, 64);
  if (!hf){
    float n2 = 0.f;
    #pragma unroll
    for (int oc=0; oc<16; ++oc) n2 += acc[oc]*acc[oc];
    float inv = 1.0f / fmaxf(sqrtf(n2), 5e-5f);
    _Float16* ho = xeh + (size_t)pix*NCR;
    _Float16* no = xenh + (size_t)pix*NCR;
    #pragma unroll
    for (int g=0; g<4; ++g){
      half4 hv, nv;
      #pragma unroll
      for (int j=0; j<4; ++j){ hv[j] = (_Float16)acc[g*4+j]; nv[j] = (_Float16)(acc[g*4+j]*inv); }
      *(half4*)(ho + g*4) = hv;
      *(half4*)(no + g*4) = nv;
    }
  }
  #pragma unroll
  for (int hh=0; hh<2; ++hh){
    int h = hf*2 + hh;
    float rv[16];
    #pragma unroll
    for (int i=0; i<16; ++i){
      float s = 0.f;
      #pragma unroll
      for (int f=0; f<16; ++f) s += acc[f]*rot[(f*NHASH + h)*16 + i];
      rv[i] = s;
    }
    float best = -1e30f; int bi = 0;
    #pragma unroll
    for (int i=0; i<16; ++i){ if (rv[i] > best){ best = rv[i]; bi = i; } }
    #pragma unroll
    for (int i=0; i<16; ++i){ float val = -rv[i]; if (val > best){ best = val; bi = 16+i; } }
    int code = bi + h*32;
    codes[((bb*NHASH + h) << 14) + l] = code;
    int tile = h*64 + (l >> 8);
    atomicAdd(&hist[bb*NKEY*NTILE + code*NTILE + tile], 1);
  }
}

__global__ __launch_bounds__(256,4) void k_yeh(const float* __restrict__ mask,
                      const float* __restrict__ w, const float* __restrict__ b,
                      const int* __restrict__ undo, _Float16* __restrict__ vs){
  int gid = blockIdx.x*256 + threadIdx.x;
  int oc0 = blockIdx.y*16;
  int bb = gid >> 14, l = gid & (NL-1);
  const float* mi = mask + (size_t)bb*NC*NL + l;
  float acc[16];
  #pragma unroll
  for (int j=0; j<16; ++j) acc[j] = b[oc0+j];
  for (int ic0=0; ic0<64; ic0+=8){
    float r[8];
    #pragma unroll
    for (int j=0; j<8; ++j) r[j] = mi[(size_t)(ic0+j)*NL];
    #pragma unroll
    for (int j=0; j<16; ++j){
      #pragma unroll
      for (int t=0; t<8; ++t) acc[j] += r[t]*w[(oc0+j)*64+ic0+t];
    }
  }
  half8 h0, h1;
  #pragma unroll
  for (int j=0; j<8; ++j){ h0[j] = (_Float16)acc[j]; h1[j] = (_Float16)acc[8+j]; }
  const int* ub = undo + bb*TOT;
  #pragma unroll
  for (int h=0; h<4; ++h){
    int pos = ub[h*NL + l];
    _Float16* vo = vs + ((size_t)bb*TOT + pos)*64 + oc0;
    *(half8*)(vo) = h0;
    *(half8*)(vo + 8) = h1;
  }
}

__global__ void k_scan(const int* __restrict__ hist, int* __restrict__ offs){
  __shared__ int part[256];
  int bb = blockIdx.x; int t = threadIdx.x;
  const int* hi = hist + (size_t)bb*NKEY*NTILE;
  int* oo = offs + (size_t)bb*NKEY*NTILE;
  int s = 0;
  for (int i=0; i<128; ++i) s += hi[t*128 + i];
  part[t] = s; __syncthreads();
  int v = s;
  for (int off=1; off<256; off<<=1){
    int u = (t >= off) ? part[t-off] : 0;
    __syncthreads();
    v += u; part[t] = v;
    __syncthreads();
  }
  int run = v - s;
  for (int i=0; i<128; ++i){ int q = hi[t*128+i]; oo[t*128+i] = run; run += q; }
}

__global__ __launch_bounds__(256) void k_scatter(const int* __restrict__ codes,
                          const int* __restrict__ offs,
                          const _Float16* __restrict__ xeh, const _Float16* __restrict__ xenh,
                          int* __restrict__ undo,
                          _Float16* __restrict__ qs, _Float16* __restrict__ ks){
  __shared__ int cnt[4][NKEY];
  int wid = threadIdx.x >> 6, lane = threadIdx.x & 63;
  int t4 = blockIdx.x;
  int bb = t4 >> 6;
  int tile = (t4 & 63)*4 + wid;
  cnt[wid][lane] = 0; cnt[wid][64+lane] = 0;
  const int* cb = codes + bb*TOT;
  const int* ob = offs + (size_t)bb*NKEY*NTILE;
  int* ub = undo + bb*TOT;
  for (int g=0; g<4; ++g){
    int j = tile*TILESZ + g*64 + lane;
    int k = cb[j];
    unsigned long long m = ~0ull;
    #pragma unroll
    for (int bit=0; bit<7; ++bit){
      unsigned long long bmask = __ballot((k >> bit) & 1);
      m &= ((k >> bit) & 1) ? bmask : ~bmask;
    }
    int rank = __popcll(m & ((1ull << lane) - 1ull));
    int leader = __ffsll((unsigned long long)m) - 1;
    int base = 0;
    if (lane == leader){
      base = cnt[wid][k];
      cnt[wid][k] = base + __popcll(m);
    }
    base = __shfl(base, leader, 64);
    int pos = ob[k*NTILE + tile] + base + rank;
    ub[j] = pos;
    int l = j & (NL-1);
    const _Float16* qp = xeh + ((size_t)bb*NL + l)*16;
    const _Float16* kp = xenh + ((size_t)bb*NL + l)*16;
    _Float16* qo = qs + ((size_t)bb*TOT + pos)*16;
    _Float16* ko = ks + ((size_t)bb*TOT + pos)*16;
    *(half8*)(qo)     = *(const half8*)(qp);
    *(half8*)(qo + 8) = *(const half8*)(qp + 8);
    *(half8*)(ko)     = *(const half8*)(kp);
    *(half8*)(ko + 8) = *(const half8*)(kp + 8);
    __threadfence_block();
  }
}

// MFMA flash attention: 128-key staging tiles, sorted operands, T14 prefetch,
// native-exp2 softmax, permuted V^T (b128 PV reads), T5 setprio around MFMA.
__global__ __launch_bounds__(512) void k_attn(
    const _Float16* __restrict__ qs, const _Float16* __restrict__ ks,
    const _Float16* __restrict__ vs,
    _Float16* __restrict__ retb, float* __restrict__ bsc){
  __shared__ _Float16 kt[128*20];
  __shared__ _Float16 vt[64*136];
  int blk = blockIdx.x;
  int qh = blk & 1; int kk = (blk >> 1) & 31; int h = (blk >> 6) & 3; int bb = blk >> 8;
  int tid = threadIdx.x;
  int w = tid >> 6, lane = tid & 63, col = lane & 15, grp = lane >> 4;
  int qbase = h*NL + kk*CHUNKSZ + qh*256 + w*32;

  half4 qfr[2]; int posq[2];
  #pragma unroll
  for (int qf=0; qf<2; ++qf){
    posq[qf] = qbase + qf*16 + col;
    qfr[qf] = *(const half4*)(qs + ((size_t)bb*TOT + posq[qf])*16 + grp*4);
    #pragma unroll
    for (int i=0; i<4; ++i) qfr[qf][i] = (_Float16)((float)qfr[qf][i] * 1.44269504f);
  }

  f32x4 O[4][2];
  #pragma unroll
  for (int a=0; a<4; ++a)
    #pragma unroll
    for (int b=0; b<2; ++b) O[a][b] = (f32x4){0.f,0.f,0.f,0.f};
  float m_[2] = {-1e30f,-1e30f};
  float ssum[2] = {0.f,0.f};

  int kx = tid & 127, c0 = (tid >> 7) * 16;
  int kxl = kx & 31;
  int vcol = (kx & 96) + (((kxl & 12) << 1) + ((kxl & 16) >> 2) + (kxl & 3));
  int kr = tid >> 1, khf = tid & 1;

  #define SPOS(jj) ({ int sec_ = (jj) >> 9; int j0_ = (jj) & 511; \
      int cc_ = kk + ((sec_==1) ? -1 : (sec_==2) ? 1 : 0); \
      cc_ = (cc_ + NCHUNKS) & (NCHUNKS-1); h*NL + cc_*CHUNKSZ + j0_; })

  half8 vv0 = *(const half8*)(vs + ((size_t)bb*TOT + SPOS(kx))*64 + c0);
  half8 vv1 = *(const half8*)(vs + ((size_t)bb*TOT + SPOS(kx))*64 + c0 + 8);
  half8 kv;
  if (tid < 256) kv = *(const half8*)(ks + ((size_t)bb*TOT + SPOS(kr))*16 + khf*8);

  for (int t=0; t<12; ++t){
    __syncthreads();
    #pragma unroll
    for (int j=0; j<8; ++j) vt[(c0+j)*136 + vcol] = vv0[j];
    #pragma unroll
    for (int j=0; j<8; ++j) vt[(c0+8+j)*136 + vcol] = vv1[j];
    if (tid < 256) *(half8*)(kt + kr*20 + khf*8) = kv;
    __syncthreads();
    if (t+1 < 12){
      int jj = (t+1)*128;
      vv0 = *(const half8*)(vs + ((size_t)bb*TOT + SPOS(jj + kx))*64 + c0);
      vv1 = *(const half8*)(vs + ((size_t)bb*TOT + SPOS(jj + kx))*64 + c0 + 8);
      if (tid < 256) kv = *(const half8*)(ks + ((size_t)bb*TOT + SPOS(jj + kr))*16 + khf*8);
    }

    #pragma unroll
    for (int hh=0; hh<2; ++hh){
      int kb0 = hh*64;
      f32x4 S[4][2];
      __builtin_amdgcn_s_setprio(1);
      #pragma unroll
      for (int kb=0; kb<4; ++kb){
        half4 ka = *(const half4*)(kt + (kb0 + kb*16 + col)*20 + grp*4);
        #pragma unroll
        for (int qf=0; qf<2; ++qf)
          S[kb][qf] = __builtin_amdgcn_mfma_f32_16x16x16f16(
              ka, qfr[qf], (f32x4){0.f,0.f,0.f,0.f}, 0, 0, 0);
      }
      __builtin_amdgcn_s_setprio(0);

      half8 pb[2][2];
      #pragma unroll
      for (int qf=0; qf<2; ++qf){
        float mtl = -1e30f;
        #pragma unroll
        for (int kb=0; kb<4; ++kb)
          #pragma unroll
          for (int i=0; i<4; ++i) mtl = fmaxf(mtl, S[kb][qf][i]);
        if (__any(mtl > m_[qf] + 11.5f)){
          float mt = fmaxf(mtl, __shfl_xor(mtl, 16, 64));
          mt = fmaxf(mt, __shfl_xor(mt, 32, 64));
          float mn = fmaxf(m_[qf], mt);
          float sc = EXP2F(m_[qf] - mn);
          ssum[qf] *= sc;
          m_[qf] = mn;
          #pragma unroll
          for (int cf=0; cf<4; ++cf)
            #pragma unroll
            for (int i=0; i<4; ++i) O[cf][qf][i] *= sc;
        }
        float ps = 0.f;
        #pragma unroll
        for (int k2=0; k2<2; ++k2){
          half8 hb;
          #pragma unroll
          for (int i=0; i<4; ++i){
            float p0 = EXP2F(S[2*k2][qf][i]   - m_[qf]);
            float p1 = EXP2F(S[2*k2+1][qf][i] - m_[qf]);
            ps += p0 + p1;
            hb[i]   = (_Float16)p0;
            hb[4+i] = (_Float16)p1;
          }
          pb[qf][k2] = hb;
        }
        ssum[qf] += ps;
      }

      __builtin_amdgcn_s_setprio(1);
      #pragma unroll
      for (int cf=0; cf<4; ++cf){
        #pragma unroll
        for (int k2=0; k2<2; ++k2){
          half8 va = *(const half8*)(vt + (cf*16 + col)*136 + kb0 + k2*32 + grp*8);
          #pragma unroll
          for (int qf=0; qf<2; ++qf)
            O[cf][qf] = __builtin_amdgcn_mfma_f32_16x16x32_f16(
                va, pb[qf][k2], O[cf][qf], 0, 0, 0);
        }
      }
      __builtin_amdgcn_s_setprio(0);
    }
  }
  #undef SPOS

  #pragma unroll
  for (int qf=0; qf<2; ++qf){
    float st = ssum[qf];
    st += __shfl_xor(st, 16, 64);
    st += __shfl_xor(st, 32, 64);
    float inv = 1.0f/st;
    size_t rb = ((size_t)bb*TOT + posq[qf])*64;
    #pragma unroll
    for (int cf=0; cf<4; ++cf){
      half4 o;
      #pragma unroll
      for (int i=0; i<4; ++i) o[i] = (_Float16)(O[cf][qf][i]*inv);
      *(half4*)(retb + rb + cf*16 + grp*4) = o;
    }
    if (grp == 0) bsc[(size_t)bb*TOT + posq[qf]] = m_[qf]*0.69314718f + logf(st);
  }
}

__global__ __launch_bounds__(256,4) void k_combine(const _Float16* __restrict__ retb,
                          const float* __restrict__ bsc,
                          const int* __restrict__ undo, const float* __restrict__ mask,
                          float* __restrict__ fea){
  int gid = blockIdx.x*256 + threadIdx.x;
  int c0 = blockIdx.y*32;
  int bb = gid >> 14; int l = gid & (NL-1);
  const int* ub = undo + bb*TOT;
  int pos[4]; float sc[4];
  #pragma unroll
  for (int h=0; h<4; ++h){ pos[h] = ub[h*NL + l]; sc[h] = bsc[bb*TOT + pos[h]]; }
  float mx = fmaxf(fmaxf(sc[0],sc[1]), fmaxf(sc[2],sc[3]));
  float e[4]; float tot = 0.f;
  #pragma unroll
  for (int h=0; h<4; ++h){ e[h] = __expf(sc[h]-mx); tot += e[h]; }
  float inv = 0.1f/tot;
  const float* mb_ = mask + (size_t)bb*NC*NL + l;
  float* fo = fea + (size_t)bb*NC*NL + l;
  const _Float16* r0 = retb + ((size_t)bb*TOT + pos[0])*NC + c0;
  const _Float16* r1 = retb + ((size_t)bb*TOT + pos[1])*NC + c0;
  const _Float16* r2 = retb + ((size_t)bb*TOT + pos[2])*NC + c0;
  const _Float16* r3 = retb + ((size_t)bb*TOT + pos[3])*NC + c0;
  #pragma unroll
  for (int g=0; g<4; ++g){
    half8 v0 = *(const half8*)(r0 + g*8);
    half8 v1 = *(const half8*)(r1 + g*8);
    half8 v2 = *(const half8*)(r2 + g*8);
    half8 v3 = *(const half8*)(r3 + g*8);
    #pragma unroll
    for (int j=0; j<8; ++j){
      int c = c0 + g*8 + j;
      float v = (float)v0[j]*e[0] + (float)v1[j]*e[1] + (float)v2[j]*e[2] + (float)v3[j]*e[3];
      fo[(size_t)c*NL] = v*inv + mb_[(size_t)c*NL];
    }
  }
}

__global__ __launch_bounds__(256,4) void k_collect(const float* __restrict__ fea,
                          const float* __restrict__ w,
                          const float* __restrict__ b, const float* __restrict__ x,
                          float* __restrict__ out){
  int gid = blockIdx.x*256 + threadIdx.x;
  int oc0 = blockIdx.y*16;
  int bb = gid >> 14, p = gid & (NL-1);
  const float* fi = fea + (size_t)bb*NC*NL + p;
  const float* xi = x + (size_t)bb*NC*NL + p;
  float acc[16];
  #pragma unroll
  for (int j=0; j<16; ++j) acc[j] = b[oc0+j];
  for (int ic0=0; ic0<64; ic0+=8){
    float r[8];
    #pragma unroll
    for (int j=0; j<8; ++j) r[j] = fi[(size_t)(ic0+j)*NL];
    #pragma unroll
    for (int j=0; j<16; ++j){
      #pragma unroll
      for (int t=0; t<8; ++t) acc[j] += r[t]*w[(oc0+j)*64+ic0+t];
    }
  }
  float* oo = out + (size_t)bb*NC*NL + p;
  #pragma unroll
  for (int j=0; j<16; ++j){
    int oc = oc0 + j;
    oo[(size_t)oc*NL] = acc[j] + xi[(size_t)oc*NL];
  }
}

// ---------------- launcher ----------------
extern "C" void kernel_launch(void* const* d_in, const int* in_sizes, int n_in,
                              void* d_out, int out_size, void* d_ws, size_t ws_size,
                              hipStream_t stream) {
  const float* x        = (const float*)d_in[0];
  const float* spa_dw   = (const float*)d_in[1];
  const float* spa_db   = (const float*)d_in[2];
  const float* s0_pw    = (const float*)d_in[3];
  const float* s0_dww   = (const float*)d_in[4];
  const float* s0_dwb   = (const float*)d_in[5];
  const float* fus_w    = (const float*)d_in[15];
  const float* fus_b    = (const float*)d_in[16];
  const float* res_w    = (const float*)d_in[17];
  const float* res_b    = (const float*)d_in[18];
  const float* ca_w1    = (const float*)d_in[19];
  const float* ca_b1    = (const float*)d_in[20];
  const float* ca_w2    = (const float*)d_in[21];
  const float* ca_b2    = (const float*)d_in[22];
  const float* c11_w    = (const float*)d_in[23];
  const float* c11_b    = (const float*)d_in[24];
  const float* match_w  = (const float*)d_in[25];
  const float* match_b  = (const float*)d_in[26];
  const float* asm_w    = (const float*)d_in[27];
  const float* asm_b    = (const float*)d_in[28];
  const float* rot      = (const float*)d_in[29];
  const float* col_w    = (const float*)d_in[30];
  const float* col_b    = (const float*)d_in[31];
  float* out = (float*)d_out;

  float* ws    = (float*)d_ws;
  float* mask  = ws + OFF_MASK;
  float* fea   = ws + OFF_FEA;
  _Float16* xeh  = (_Float16*)(ws + OFF_XEH);
  _Float16* xenh = (_Float16*)(ws + OFF_XENH);
  _Float16* vsort = (_Float16*)(ws + OFF_VS);
  _Float16* qsort = (_Float16*)(ws + OFF_QS);
  _Float16* ksort = (_Float16*)(ws + OFF_KS);
  _Float16* retb = (_Float16*)(ws + OFF_RET);
  float* bsc   = ws + OFF_BSC;
  int*   ib    = (int*)(ws + OFF_INT);
  int* codes   = ib + IOFF_CODES;
  int* undo    = ib + IOFF_UNDO;
  int* hist    = ib + IOFF_HIST;
  int* offs    = ib + IOFF_OFFS;
  float* cay   = ws + OFF_CAY;
  float* cas   = ws + OFF_CAS;
  float* crw   = ws + OFF_CRW;
  float* crb   = ws + OFF_CRB;
  float* xr    = ws + OFF_XR;
  float* feats = ws + OFF_FEATS;
  float* ptmp  = ws + OFF_PTMP;
  float* dwt   = ws + OFF_DWT;
  float* pre1  = ws + OFF_PRE1;

  // ---- phase 1 ----
  k_xr<<<(NB*NL*2)/256, 256, 0, stream>>>(x, spa_dw, spa_db, xr);
  k_wprod<<<16, 256, 0, stream>>>(c11_w, c11_b, res_w, res_b, crw, crb);
  k_s0<<<dim3((NB*NL)/256, 2), 256, 0, stream>>>(xr, s0_pw, s0_dww, s0_dwb, feats);
  k_pw16_all<<<(6*NB*NL2)/256, 256, 0, stream>>>(xr,
      (const float*)d_in[6], (const float*)d_in[9], (const float*)d_in[12], ptmp);
  k_dw_all<<<(6*NB*NCR*NL2)/256, 256, 0, stream>>>(ptmp,
      (const float*)d_in[7], (const float*)d_in[8],
      (const float*)d_in[10], (const float*)d_in[11],
      (const float*)d_in[13], (const float*)d_in[14], dwt);
  k_up_all<<<(6*NB*NCR*NL)/256, 256, 0, stream>>>(dwt, feats);
  k_camean<<<NB*NC, 256, 0, stream>>>(x, cay);
  k_camlp<<<1, 128, 0, stream>>>(cay, ca_w1, ca_b1, ca_w2, ca_b2, cas);
  k_attnmul<<<dim3((NB*NL)/256, 4), 256, 0, stream>>>(x, feats, fus_w, fus_b, cas, pre1);
  k_mask<<<dim3((NB*NL)/256, 4), 256, 0, stream>>>(pre1, c11_w, crw, crb, x, mask);

  // ---- phase 2 ----
  (void)hipMemsetAsync(hist, 0, (size_t)NB*NKEY*NTILE*sizeof(int), stream);
  k_xe<<<(NB*NL*2)/256, 256, 0, stream>>>(mask, match_w, match_b, rot, xeh, xenh, codes, hist);
  k_scan<<<NB, 256, 0, stream>>>(hist, offs);
  k_scatter<<<NB*NTILE/4, 256, 0, stream>>>(codes, offs, xeh, xenh, undo, qsort, ksort);
  k_yeh<<<dim3((NB*NL)/256, 4), 256, 0, stream>>>(mask, asm_w, asm_b, undo, vsort);
  k_attn<<<NB*NHASH*NCHUNKS*2, 512, 0, stream>>>(qsort, ksort, vsort, retb, bsc);
  k_combine<<<dim3((NB*NL)/256, 2), 256, 0, stream>>>(retb, bsc, undo, mask, fea);
  k_collect<<<dim3((NB*NL)/256, 4), 256, 0, stream>>>(fea, col_w, col_b, x, out);
}